// Round 1
// baseline (1525.839 us; speedup 1.0000x reference)
//
#include <hip/hip_runtime.h>

#define NN 100000
#define HH 128
#define GG 64
#define EPS 1e-5f

// ---------------- CSR build ----------------
__global__ void k_count(const int* __restrict__ dst, int* __restrict__ cnt, int E) {
    int i = blockIdx.x * blockDim.x + threadIdx.x;
    if (i < E) atomicAdd(&cnt[dst[i]], 1);
}

__global__ __launch_bounds__(512) void k_scanA(const int* __restrict__ cnt, int* __restrict__ tmp,
                                               int* __restrict__ bsum, int n) {
    __shared__ int s[512];
    int t = threadIdx.x;
    int i = blockIdx.x * 512 + t;
    s[t] = (i < n) ? cnt[i] : 0;
    __syncthreads();
    for (int o = 1; o < 512; o <<= 1) {
        int u = (t >= o) ? s[t - o] : 0;
        __syncthreads();
        s[t] += u;
        __syncthreads();
    }
    if (i < n) tmp[i] = s[t];
    if (t == 511) bsum[blockIdx.x] = s[511];
}

__global__ __launch_bounds__(512) void k_scanB(int* __restrict__ bsum, int nb) {
    __shared__ int s[512];
    int t = threadIdx.x;
    s[t] = (t < nb) ? bsum[t] : 0;
    __syncthreads();
    for (int o = 1; o < 512; o <<= 1) {
        int u = (t >= o) ? s[t - o] : 0;
        __syncthreads();
        s[t] += u;
        __syncthreads();
    }
    if (t < nb) bsum[t] = s[t];
}

__global__ void k_scanC(const int* __restrict__ tmp, const int* __restrict__ bsum,
                        int* __restrict__ rowptr, int n) {
    int i = blockIdx.x * blockDim.x + threadIdx.x;
    if (i < n) {
        int b = i >> 9;
        int off = (b > 0) ? bsum[b - 1] : 0;
        rowptr[i + 1] = tmp[i] + off;
        if (i == 0) rowptr[0] = 0;
    }
}

__global__ void k_dinv(const int* __restrict__ cnt, float* __restrict__ dinv, int n) {
    int i = blockIdx.x * blockDim.x + threadIdx.x;
    if (i < n) dinv[i] = 1.0f / sqrtf((float)(cnt[i] + 1));
}

__global__ void k_fill(const int* __restrict__ src, const int* __restrict__ dst,
                       const int* __restrict__ rowptr, int* __restrict__ cursor,
                       const float* __restrict__ dinv, int* __restrict__ colA,
                       float* __restrict__ normv, int E) {
    int e = blockIdx.x * blockDim.x + threadIdx.x;
    if (e < E) {
        int s0 = src[e], d0 = dst[e];
        int p = atomicAdd(&cursor[d0], 1);
        int idx = rowptr[d0] + p;
        colA[idx] = s0;
        normv[idx] = dinv[s0] * dinv[d0];
    }
}

// ---------------- GEMM: C[n x 128] = A[n x 128] @ W[128 x 128] ----------------
// ACT==0: plain. ACT==1: C = tanh(A@W + bias)
#define FMA_ROW(i, a)                       \
    acc[i][0] = fmaf(a, w0.x, acc[i][0]);   \
    acc[i][1] = fmaf(a, w0.y, acc[i][1]);   \
    acc[i][2] = fmaf(a, w0.z, acc[i][2]);   \
    acc[i][3] = fmaf(a, w0.w, acc[i][3]);   \
    acc[i][4] = fmaf(a, w1.x, acc[i][4]);   \
    acc[i][5] = fmaf(a, w1.y, acc[i][5]);   \
    acc[i][6] = fmaf(a, w1.z, acc[i][6]);   \
    acc[i][7] = fmaf(a, w1.w, acc[i][7]);

template <int ACT>
__global__ __launch_bounds__(256) void k_gemm(const float* __restrict__ A, const float* __restrict__ W,
                                              const float* __restrict__ bias, float* __restrict__ C, int n) {
    __shared__ float hl[64][128];
    int tb = blockIdx.x * 64;
    int t = threadIdx.x;
    int rows = n - tb; if (rows > 64) rows = 64;
    for (int idx = t; idx < 64 * 32; idx += 256) {
        int r = idx >> 5, c4 = (idx & 31) << 2;
        if (r < rows)
            *(float4*)&hl[r][c4] = *(const float4*)&A[(size_t)(tb + r) * HH + c4];
    }
    __syncthreads();
    int tx = t & 15;   // cols 8*tx .. 8*tx+7
    int ty = t >> 4;   // rows ty + 16*i
    float acc[4][8] = {};
    for (int k = 0; k < 128; ++k) {
        const float4 w0 = *(const float4*)&W[k * HH + (tx << 3)];
        const float4 w1 = *(const float4*)&W[k * HH + (tx << 3) + 4];
        float a0 = hl[ty][k];
        float a1 = hl[ty + 16][k];
        float a2 = hl[ty + 32][k];
        float a3 = hl[ty + 48][k];
        FMA_ROW(0, a0)
        FMA_ROW(1, a1)
        FMA_ROW(2, a2)
        FMA_ROW(3, a3)
    }
#pragma unroll
    for (int i = 0; i < 4; ++i) {
        int r = tb + ty + 16 * i;
        if (r < n) {
            float vout[8];
#pragma unroll
            for (int j = 0; j < 8; ++j) {
                float v = acc[i][j];
                if (ACT == 1) v = tanhf(v + bias[(tx << 3) + j]);
                vout[j] = v;
            }
            float4 o0 = {vout[0], vout[1], vout[2], vout[3]};
            float4 o1 = {vout[4], vout[5], vout[6], vout[7]};
            *(float4*)&C[(size_t)r * HH + (tx << 3)] = o0;
            *(float4*)&C[(size_t)r * HH + (tx << 3) + 4] = o1;
        }
    }
}

// ---------------- Aggregation: agg[i] = norm_self*z[i] + sum_e norm[e]*z[col[e]] + bias ----------------
__global__ __launch_bounds__(256) void k_agg(const float* __restrict__ z, const int* __restrict__ rowptr,
                                             const int* __restrict__ colA, const float* __restrict__ normv,
                                             const float* __restrict__ dinv, const float* __restrict__ bias,
                                             float* __restrict__ agg, int n) {
    int wid = (int)((blockIdx.x * (size_t)blockDim.x + threadIdx.x) >> 6);
    int lane = threadIdx.x & 63;
    if (wid >= n) return;
    int beg = rowptr[wid], end = rowptr[wid + 1];
    float di = dinv[wid];
    float wself = di * di;
    float2 zv = *(const float2*)&z[(size_t)wid * HH + lane * 2];
    float ax = zv.x * wself, ay = zv.y * wself;
    for (int e = beg; e < end; ++e) {
        int s0 = colA[e];
        float w = normv[e];
        float2 v = *(const float2*)&z[(size_t)s0 * HH + lane * 2];
        ax = fmaf(v.x, w, ax);
        ay = fmaf(v.y, w, ay);
    }
    float2 b2 = *(const float2*)&bias[lane * 2];
    float2 o = {ax + b2.x, ay + b2.y};
    *(float2*)&agg[(size_t)wid * HH + lane * 2] = o;
}

// ---------------- BatchNorm ----------------
__global__ __launch_bounds__(256) void k_bnstats(const float* __restrict__ agg, float* __restrict__ colsum,
                                                 float* __restrict__ colsq, int n) {
    int t = threadIdx.x;
    int col = t & 127, sub = t >> 7;
    int rpb = (n + gridDim.x - 1) / gridDim.x;
    int r0 = blockIdx.x * rpb;
    int r1 = r0 + rpb; if (r1 > n) r1 = n;
    float s = 0.f, q = 0.f;
    for (int r = r0 + sub; r < r1; r += 2) {
        float v = agg[(size_t)r * HH + col];
        s += v;
        q = fmaf(v, v, q);
    }
    __shared__ float ls[256], lq[256];
    ls[t] = s; lq[t] = q;
    __syncthreads();
    if (t < 128) {
        atomicAdd(&colsum[col], ls[t] + ls[t + 128]);
        atomicAdd(&colsq[col], lq[t] + lq[t + 128]);
    }
}

__global__ void k_bnfinal(const float* __restrict__ colsum, const float* __restrict__ colsq,
                          const float* __restrict__ g, const float* __restrict__ b,
                          float* __restrict__ Ac, float* __restrict__ Bc, int n) {
    int c = threadIdx.x;
    float mean = colsum[c] / (float)n;
    float var = colsq[c] / (float)n - mean * mean;
    float istd = 1.0f / sqrtf(var + EPS);
    float A = istd * g[c];
    Ac[c] = A;
    Bc[c] = b[c] - mean * A;
}

__global__ void k_bnapply(const float* __restrict__ agg, const float* __restrict__ Ac,
                          const float* __restrict__ Bc, const float* __restrict__ hin,
                          float* __restrict__ hout, int nvec4, int residual) {
    int i = blockIdx.x * blockDim.x + threadIdx.x;
    if (i >= nvec4) return;
    float4 v = *(const float4*)&agg[(size_t)i * 4];
    int c = (i * 4) & 127;
    float4 A = *(const float4*)&Ac[c];
    float4 B = *(const float4*)&Bc[c];
    v.x = fmaxf(fmaf(v.x, A.x, B.x), 0.f);
    v.y = fmaxf(fmaf(v.y, A.y, B.y), 0.f);
    v.z = fmaxf(fmaf(v.z, A.z, B.z), 0.f);
    v.w = fmaxf(fmaf(v.w, A.w, B.w), 0.f);
    if (residual) {
        float4 h0 = *(const float4*)&hin[(size_t)i * 4];
        v.x += h0.x; v.y += h0.y; v.z += h0.z; v.w += h0.w;
    }
    *(float4*)&hout[(size_t)i * 4] = v;
}

// ---------------- Attention ----------------
__global__ __launch_bounds__(256) void k_att_gemv(const float* __restrict__ T, const float* __restrict__ w2,
                                                  const float* __restrict__ b2, float* __restrict__ apre, int n) {
    int wid = (int)((blockIdx.x * (size_t)blockDim.x + threadIdx.x) >> 6);
    int lane = threadIdx.x & 63;
    if (wid >= n) return;
    const float* row = &T[(size_t)wid * HH];
    float p = fmaf(row[lane], w2[lane], row[lane + 64] * w2[lane + 64]);
#pragma unroll
    for (int o = 32; o > 0; o >>= 1) p += __shfl_down(p, o);
    if (lane == 0) apre[wid] = p + b2[0];
}

__global__ __launch_bounds__(256) void k_redmax(const float* __restrict__ a, float* __restrict__ pmax, int n) {
    float m = -3.4e38f;
    for (int i = blockIdx.x * blockDim.x + threadIdx.x; i < n; i += gridDim.x * blockDim.x)
        m = fmaxf(m, a[i]);
    __shared__ float s[256];
    s[threadIdx.x] = m;
    __syncthreads();
    for (int o = 128; o > 0; o >>= 1) {
        if (threadIdx.x < o) s[threadIdx.x] = fmaxf(s[threadIdx.x], s[threadIdx.x + o]);
        __syncthreads();
    }
    if (threadIdx.x == 0) pmax[blockIdx.x] = s[0];
}

__global__ __launch_bounds__(256) void k_redmax2(const float* __restrict__ pmax, float* __restrict__ MS, int nb) {
    __shared__ float s[256];
    int t = threadIdx.x;
    s[t] = (t < nb) ? pmax[t] : -3.4e38f;
    __syncthreads();
    for (int o = 128; o > 0; o >>= 1) {
        if (t < o) s[t] = fmaxf(s[t], s[t + o]);
        __syncthreads();
    }
    if (t == 0) MS[0] = s[0];
}

__global__ __launch_bounds__(256) void k_redsum(const float* __restrict__ a, const float* __restrict__ MS,
                                                float* __restrict__ psum, int n) {
    float M = MS[0];
    float acc = 0.f;
    for (int i = blockIdx.x * blockDim.x + threadIdx.x; i < n; i += gridDim.x * blockDim.x)
        acc += expf(a[i] - M);
    __shared__ float s[256];
    s[threadIdx.x] = acc;
    __syncthreads();
    for (int o = 128; o > 0; o >>= 1) {
        if (threadIdx.x < o) s[threadIdx.x] += s[threadIdx.x + o];
        __syncthreads();
    }
    if (threadIdx.x == 0) psum[blockIdx.x] = s[0];
}

__global__ __launch_bounds__(256) void k_redsum2(const float* __restrict__ psum, float* __restrict__ MS, int nb) {
    __shared__ float s[256];
    int t = threadIdx.x;
    s[t] = (t < nb) ? psum[t] : 0.f;
    __syncthreads();
    for (int o = 128; o > 0; o >>= 1) {
        if (t < o) s[t] += s[t + o];
        __syncthreads();
    }
    if (t == 0) MS[1] = s[0];
}

// ---------------- Pooling (batch sorted): pooled[g][c] = sum_i exp(apre[i]-M)*h[i][c] ----------------
__global__ __launch_bounds__(256) void k_pool(const float* __restrict__ h, const float* __restrict__ apre,
                                              const int* __restrict__ batch, const float* __restrict__ MS,
                                              float* __restrict__ pooled, float* __restrict__ counts, int n) {
    float M = MS[0];
    int t = threadIdx.x;
    int col = t & 127, sub = t >> 7;
    int rpb = (n + gridDim.x - 1) / gridDim.x;
    int r0 = blockIdx.x * rpb;
    int r1 = r0 + rpb; if (r1 > n) r1 = n;
    float acc = 0.f, cntf = 0.f;
    int cur = -1;
    for (int r = r0 + sub; r < r1; r += 2) {
        int g = batch[r];
        if (g != cur) {
            if (cur >= 0) {
                atomicAdd(&pooled[cur * HH + col], acc);
                if (col == 0) atomicAdd(&counts[cur], cntf);
            }
            cur = g; acc = 0.f; cntf = 0.f;
        }
        float s = expf(apre[r] - M);
        acc = fmaf(h[(size_t)r * HH + col], s, acc);
        cntf += 1.0f;
    }
    if (cur >= 0) {
        atomicAdd(&pooled[cur * HH + col], acc);
        if (col == 0) atomicAdd(&counts[cur], cntf);
    }
}

// ---------------- Final MLP: out[g] = relu(p@W1+b1)@W2+b2 ----------------
__global__ __launch_bounds__(128) void k_mlp(const float* __restrict__ pooled, const float* __restrict__ counts,
                                             const float* __restrict__ MS, const float* __restrict__ W1,
                                             const float* __restrict__ b1, const float* __restrict__ W2,
                                             const float* __restrict__ b2, float* __restrict__ out) {
    int g = blockIdx.x;
    int t = threadIdx.x;
    __shared__ float p[128], t1[128];
    float S = MS[1];
    float c = fmaxf(counts[g], 1.0f);
    p[t] = pooled[g * HH + t] / (S * c);
    __syncthreads();
    float acc = b1[t];
    for (int k = 0; k < 128; ++k) acc = fmaf(p[k], W1[k * HH + t], acc);
    t1[t] = fmaxf(acc, 0.f);
    __syncthreads();
    float acc2 = b2[t];
    for (int j = 0; j < 128; ++j) acc2 = fmaf(t1[j], W2[j * HH + t], acc2);
    out[g * HH + t] = acc2;
}

extern "C" void kernel_launch(void* const* d_in, const int* in_sizes, int n_in,
                              void* d_out, int out_size, void* d_ws, size_t ws_size,
                              hipStream_t stream) {
    const float* x       = (const float*)d_in[0];
    const int*   ei      = (const int*)d_in[1];
    const int*   batch   = (const int*)d_in[2];
    const float* conv_w  = (const float*)d_in[3];
    const float* conv_b  = (const float*)d_in[4];
    const float* bn_g    = (const float*)d_in[5];
    const float* bn_b    = (const float*)d_in[6];
    const float* attn_w1 = (const float*)d_in[7];
    const float* attn_b1 = (const float*)d_in[8];
    const float* attn_w2 = (const float*)d_in[9];
    const float* attn_b2 = (const float*)d_in[10];
    const float* proj_w1 = (const float*)d_in[11];
    const float* proj_b1 = (const float*)d_in[12];
    const float* proj_w2 = (const float*)d_in[13];
    const float* proj_b2 = (const float*)d_in[14];

    const int E = in_sizes[1] / 2;
    const int n = in_sizes[2];
    const int* srcp = ei;
    const int* dstp = ei + E;

    // ---- workspace layout ----
    char* base = (char*)d_ws;
    size_t off = 0;
    auto alloc = [&](size_t bytes) -> char* {
        char* p = base + off;
        off = (off + bytes + 511) & ~(size_t)511;
        return p;
    };
    int*   cnt     = (int*)alloc((size_t)n * 4);
    int*   rowptr  = (int*)alloc((size_t)(n + 1) * 4);
    int*   cursor  = (int*)alloc((size_t)n * 4);
    int*   tmp     = (int*)alloc((size_t)n * 4);
    int*   bsum    = (int*)alloc(512 * 4);
    float* dinv    = (float*)alloc((size_t)n * 4);
    int*   colA    = (int*)alloc((size_t)E * 4);
    float* normv   = (float*)alloc((size_t)E * 4);
    float* h       = (float*)alloc((size_t)n * HH * 4);
    float* z       = (float*)alloc((size_t)n * HH * 4);
    float* agg     = (float*)alloc((size_t)n * HH * 4);
    float* colsum  = (float*)alloc(512);
    float* colsq   = (float*)alloc(512);
    float* Ac      = (float*)alloc(512);
    float* Bc      = (float*)alloc(512);
    float* apre    = (float*)alloc((size_t)n * 4);
    float* pmax    = (float*)alloc(1024);
    float* psum    = (float*)alloc(1024);
    float* MS      = (float*)alloc(64);
    float* pooled  = (float*)alloc(GG * HH * 4);
    float* counts  = (float*)alloc(GG * 4);

    const int eGrid   = (E + 255) / 256;
    const int nGrid   = (n + 255) / 256;
    const int nbScan  = (n + 511) / 512;
    const int gemmGrid = (n + 63) / 64;
    const int waveGrid = (n + 3) / 4;       // 4 waves (nodes) per 256-thread block
    const int bnGrid   = (n * HH / 4 + 255) / 256;

    // ---- CSR build ----
    hipMemsetAsync(cnt, 0, (size_t)n * 4, stream);
    hipMemsetAsync(cursor, 0, (size_t)n * 4, stream);
    k_count<<<eGrid, 256, 0, stream>>>(dstp, cnt, E);
    k_scanA<<<nbScan, 512, 0, stream>>>(cnt, tmp, bsum, n);
    k_scanB<<<1, 512, 0, stream>>>(bsum, nbScan);
    k_scanC<<<nGrid, 256, 0, stream>>>(tmp, bsum, rowptr, n);
    k_dinv<<<nGrid, 256, 0, stream>>>(cnt, dinv, n);
    k_fill<<<eGrid, 256, 0, stream>>>(srcp, dstp, rowptr, cursor, dinv, colA, normv, E);

    // ---- GCN layers ----
    for (int l = 0; l < 3; ++l) {
        const float* A = (l == 0) ? x : h;
        k_gemm<0><<<gemmGrid, 256, 0, stream>>>(A, conv_w + (size_t)l * HH * HH, nullptr, z, n);
        k_agg<<<waveGrid, 256, 0, stream>>>(z, rowptr, colA, normv, dinv, conv_b + l * HH, agg, n);
        hipMemsetAsync(colsum, 0, 1024, stream);  // colsum + colsq contiguous (512-pad each)
        hipMemsetAsync(colsq, 0, 512, stream);
        k_bnstats<<<256, 256, 0, stream>>>(agg, colsum, colsq, n);
        k_bnfinal<<<1, 128, 0, stream>>>(colsum, colsq, bn_g + l * HH, bn_b + l * HH, Ac, Bc, n);
        k_bnapply<<<bnGrid, 256, 0, stream>>>(agg, Ac, Bc, h, h, n * HH / 4, (l > 0) ? 1 : 0);
    }

    // ---- attention ----
    k_gemm<1><<<gemmGrid, 256, 0, stream>>>(h, attn_w1, attn_b1, z, n);   // T = tanh(h@W1+b1)
    k_att_gemv<<<waveGrid, 256, 0, stream>>>(z, attn_w2, attn_b2, apre, n);
    k_redmax<<<256, 256, 0, stream>>>(apre, pmax, n);
    k_redmax2<<<1, 256, 0, stream>>>(pmax, MS, 256);
    k_redsum<<<256, 256, 0, stream>>>(apre, MS, psum, n);
    k_redsum2<<<1, 256, 0, stream>>>(psum, MS, 256);

    // ---- pooling + MLP ----
    hipMemsetAsync(pooled, 0, GG * HH * 4, stream);
    hipMemsetAsync(counts, 0, GG * 4, stream);
    k_pool<<<128, 256, 0, stream>>>(h, apre, batch, MS, pooled, counts, n);
    k_mlp<<<GG, 128, 0, stream>>>(pooled, counts, MS, proj_w1, proj_b1, proj_w2, proj_b2, (float*)d_out);
}

// Round 2
// 1321.119 us; speedup vs baseline: 1.1550x; 1.1550x over previous
//
#include <hip/hip_runtime.h>

#define HH 128
#define GG 64
#define EPS 1e-5f

// ---------------- CSR build ----------------
__global__ void k_count(const int* __restrict__ dst, int* __restrict__ cnt, int E) {
    int i = blockIdx.x * blockDim.x + threadIdx.x;
    if (i < E) atomicAdd(&cnt[dst[i]], 1);
}

__global__ __launch_bounds__(512) void k_scanA(const int* __restrict__ cnt, int* __restrict__ tmp,
                                               int* __restrict__ bsum, int n) {
    __shared__ int s[512];
    int t = threadIdx.x;
    int i = blockIdx.x * 512 + t;
    s[t] = (i < n) ? cnt[i] : 0;
    __syncthreads();
    for (int o = 1; o < 512; o <<= 1) {
        int u = (t >= o) ? s[t - o] : 0;
        __syncthreads();
        s[t] += u;
        __syncthreads();
    }
    if (i < n) tmp[i] = s[t];
    if (t == 511) bsum[blockIdx.x] = s[511];
}

__global__ __launch_bounds__(512) void k_scanB(int* __restrict__ bsum, int nb) {
    __shared__ int s[512];
    int t = threadIdx.x;
    s[t] = (t < nb) ? bsum[t] : 0;
    __syncthreads();
    for (int o = 1; o < 512; o <<= 1) {
        int u = (t >= o) ? s[t - o] : 0;
        __syncthreads();
        s[t] += u;
        __syncthreads();
    }
    if (t < nb) bsum[t] = s[t];
}

// rowptr + dinv fused
__global__ void k_scanC(const int* __restrict__ tmp, const int* __restrict__ bsum,
                        const int* __restrict__ cnt, int* __restrict__ rowptr,
                        float* __restrict__ dinv, int n) {
    int i = blockIdx.x * blockDim.x + threadIdx.x;
    if (i < n) {
        int b = i >> 9;
        int off = (b > 0) ? bsum[b - 1] : 0;
        rowptr[i + 1] = tmp[i] + off;
        if (i == 0) rowptr[0] = 0;
        dinv[i] = rsqrtf((float)(cnt[i] + 1));
    }
}

// fill packed (col, norm) pairs
__global__ void k_fill(const int* __restrict__ src, const int* __restrict__ dst,
                       const int* __restrict__ rowptr, int* __restrict__ cursor,
                       const float* __restrict__ dinv, int2* __restrict__ epk, int E) {
    int e = blockIdx.x * blockDim.x + threadIdx.x;
    if (e < E) {
        int s0 = src[e], d0 = dst[e];
        int p = atomicAdd(&cursor[d0], 1);
        int idx = rowptr[d0] + p;
        epk[idx] = make_int2(s0, __float_as_int(dinv[s0] * dinv[d0]));
    }
}

// ---------------- GEMM: C[n x 128] = A[n x 128] @ W[128 x 128] ----------------
// ACT==0: C = A@W (raw).  ACT==1: apre[r] = tanh(A@W + b1) @ w2 + b2  (C is apre[n])
#define FMA_ROW(i, a)                       \
    acc[i][0] = fmaf(a, w0.x, acc[i][0]);   \
    acc[i][1] = fmaf(a, w0.y, acc[i][1]);   \
    acc[i][2] = fmaf(a, w0.z, acc[i][2]);   \
    acc[i][3] = fmaf(a, w0.w, acc[i][3]);   \
    acc[i][4] = fmaf(a, w1.x, acc[i][4]);   \
    acc[i][5] = fmaf(a, w1.y, acc[i][5]);   \
    acc[i][6] = fmaf(a, w1.z, acc[i][6]);   \
    acc[i][7] = fmaf(a, w1.w, acc[i][7]);

template <int ACT>
__global__ __launch_bounds__(256, 2) void k_gemm(const float* __restrict__ A, const float* __restrict__ W,
                                                 const float* __restrict__ bias, float* __restrict__ C,
                                                 const float* __restrict__ w2, const float* __restrict__ b2,
                                                 int n) {
    __shared__ float hl[64][128];   // A tile
    __shared__ float Ws[64][128];   // W k-chunk
    int tb = blockIdx.x * 64;
    int t = threadIdx.x;
    int rows = n - tb; if (rows > 64) rows = 64;
    for (int idx = t; idx < 64 * 32; idx += 256) {
        int r = idx >> 5, c4 = (idx & 31) << 2;
        if (r < rows)
            *(float4*)&hl[r][c4] = *(const float4*)&A[(size_t)(tb + r) * HH + c4];
    }
    int tx = t & 15;       // owns cols 8*tx..8*tx+7
    int ty = t >> 4;       // owns rows ty + 16*i
    int tx8 = tx << 3;
    float acc[4][8] = {};
    for (int kc = 0; kc < 2; ++kc) {
        __syncthreads();   // hl ready (kc=0) / previous chunk compute done (kc=1)
        for (int idx = t; idx < 64 * 32; idx += 256) {
            int r = idx >> 5, c4 = (idx & 31) << 2;
            *(float4*)&Ws[r][c4] = *(const float4*)&W[(size_t)(kc * 64 + r) * HH + c4];
        }
        __syncthreads();
        int kb = kc * 64;
        for (int k = 0; k < 64; ++k) {
            float4 w0 = *(const float4*)&Ws[k][tx8];
            float4 w1 = *(const float4*)&Ws[k][tx8 + 4];
            float a0 = hl[ty][kb + k];
            float a1 = hl[ty + 16][kb + k];
            float a2 = hl[ty + 32][kb + k];
            float a3 = hl[ty + 48][kb + k];
            FMA_ROW(0, a0)
            FMA_ROW(1, a1)
            FMA_ROW(2, a2)
            FMA_ROW(3, a3)
        }
    }
    if (ACT == 0) {
#pragma unroll
        for (int i = 0; i < 4; ++i) {
            int r = tb + ty + 16 * i;
            if (r < n) {
                float4 o0 = {acc[i][0], acc[i][1], acc[i][2], acc[i][3]};
                float4 o1 = {acc[i][4], acc[i][5], acc[i][6], acc[i][7]};
                *(float4*)&C[(size_t)r * HH + tx8] = o0;
                *(float4*)&C[(size_t)r * HH + tx8 + 4] = o1;
            }
        }
    } else {
        // fused attention GEMV: apre[r] = sum_c tanh(acc+b1[c]) * w2[c] + b2
        float b1v[8], w2v[8];
#pragma unroll
        for (int j = 0; j < 8; ++j) { b1v[j] = bias[tx8 + j]; w2v[j] = w2[tx8 + j]; }
        float b2s = b2[0];
#pragma unroll
        for (int i = 0; i < 4; ++i) {
            float s = 0.f;
#pragma unroll
            for (int j = 0; j < 8; ++j)
                s = fmaf(tanhf(acc[i][j] + b1v[j]), w2v[j], s);
            s += __shfl_xor(s, 1);
            s += __shfl_xor(s, 2);
            s += __shfl_xor(s, 4);
            s += __shfl_xor(s, 8);
            int r = tb + ty + 16 * i;
            if (tx == 0 && r < n) C[r] = s + b2s;
        }
    }
}

// ---------------- Aggregation ----------------
// wave = 1 node; lanes split into two halves of 32; half h processes edges beg+h, beg+h+2, ...
// each lane holds float4 (4 cols); merge halves via shfl_xor(32).
__global__ __launch_bounds__(256) void k_agg(const float* __restrict__ z, const int* __restrict__ rowptr,
                                             const int2* __restrict__ epk, const float* __restrict__ dinv,
                                             const float* __restrict__ bias, float* __restrict__ agg, int n) {
    int wid = (int)((blockIdx.x * (size_t)blockDim.x + threadIdx.x) >> 6);
    if (wid >= n) return;
    int lane = threadIdx.x & 63;
    int half = lane >> 5;
    int c0 = (lane & 31) << 2;
    int beg = rowptr[wid], end = rowptr[wid + 1];
    float4 acc = {0.f, 0.f, 0.f, 0.f};
    if (half == 0) {
        float di = dinv[wid];
        float ws = di * di;
        float4 zs = *(const float4*)&z[(size_t)wid * HH + c0];
        acc.x = zs.x * ws; acc.y = zs.y * ws; acc.z = zs.z * ws; acc.w = zs.w * ws;
    }
    int e = beg + half;
    for (; e + 2 < end; e += 4) {
        int2 p0 = epk[e];
        int2 p1 = epk[e + 2];
        float4 v0 = *(const float4*)&z[(size_t)p0.x * HH + c0];
        float4 v1 = *(const float4*)&z[(size_t)p1.x * HH + c0];
        float w0 = __int_as_float(p0.y);
        float w1 = __int_as_float(p1.y);
        acc.x = fmaf(v0.x, w0, acc.x); acc.y = fmaf(v0.y, w0, acc.y);
        acc.z = fmaf(v0.z, w0, acc.z); acc.w = fmaf(v0.w, w0, acc.w);
        acc.x = fmaf(v1.x, w1, acc.x); acc.y = fmaf(v1.y, w1, acc.y);
        acc.z = fmaf(v1.z, w1, acc.z); acc.w = fmaf(v1.w, w1, acc.w);
    }
    if (e < end) {
        int2 p0 = epk[e];
        float4 v0 = *(const float4*)&z[(size_t)p0.x * HH + c0];
        float w0 = __int_as_float(p0.y);
        acc.x = fmaf(v0.x, w0, acc.x); acc.y = fmaf(v0.y, w0, acc.y);
        acc.z = fmaf(v0.z, w0, acc.z); acc.w = fmaf(v0.w, w0, acc.w);
    }
    acc.x += __shfl_xor(acc.x, 32);
    acc.y += __shfl_xor(acc.y, 32);
    acc.z += __shfl_xor(acc.z, 32);
    acc.w += __shfl_xor(acc.w, 32);
    if (half == 0) {
        float4 b4 = *(const float4*)&bias[c0];
        acc.x += b4.x; acc.y += b4.y; acc.z += b4.z; acc.w += b4.w;
        *(float4*)&agg[(size_t)wid * HH + c0] = acc;
    }
}

// ---------------- BatchNorm ----------------
__global__ __launch_bounds__(256) void k_bnstats(const float* __restrict__ agg, float* __restrict__ colsum,
                                                 float* __restrict__ colsq, int n) {
    int t = threadIdx.x;
    int col = t & 127, sub = t >> 7;
    int rpb = (n + gridDim.x - 1) / gridDim.x;
    int r0 = blockIdx.x * rpb;
    int r1 = r0 + rpb; if (r1 > n) r1 = n;
    float s = 0.f, q = 0.f;
    for (int r = r0 + sub; r < r1; r += 2) {
        float v = agg[(size_t)r * HH + col];
        s += v;
        q = fmaf(v, v, q);
    }
    __shared__ float ls[256], lq[256];
    ls[t] = s; lq[t] = q;
    __syncthreads();
    if (t < 128) {
        atomicAdd(&colsum[col], ls[t] + ls[t + 128]);
        atomicAdd(&colsq[col], lq[t] + lq[t + 128]);
    }
}

// BN apply (+fused scale/shift computation) + ReLU + optional residual
__global__ void k_bnapply(const float* __restrict__ agg, const float* __restrict__ colsum,
                          const float* __restrict__ colsq, const float* __restrict__ g,
                          const float* __restrict__ b, const float* __restrict__ hin,
                          float* __restrict__ hout, int n, int residual) {
    int i = blockIdx.x * blockDim.x + threadIdx.x;
    int nvec4 = n * (HH / 4);
    if (i >= nvec4) return;
    int c = (i << 2) & 127;
    float4 cs = *(const float4*)&colsum[c];
    float4 cq = *(const float4*)&colsq[c];
    float4 gg = *(const float4*)&g[c];
    float4 bb = *(const float4*)&b[c];
    float inv_n = 1.0f / (float)n;
    float m0 = cs.x * inv_n, m1 = cs.y * inv_n, m2 = cs.z * inv_n, m3 = cs.w * inv_n;
    float A0 = rsqrtf(cq.x * inv_n - m0 * m0 + EPS) * gg.x;
    float A1 = rsqrtf(cq.y * inv_n - m1 * m1 + EPS) * gg.y;
    float A2 = rsqrtf(cq.z * inv_n - m2 * m2 + EPS) * gg.z;
    float A3 = rsqrtf(cq.w * inv_n - m3 * m3 + EPS) * gg.w;
    float B0 = bb.x - m0 * A0, B1 = bb.y - m1 * A1, B2 = bb.z - m2 * A2, B3 = bb.w - m3 * A3;
    float4 v = *(const float4*)&agg[(size_t)i * 4];
    v.x = fmaxf(fmaf(v.x, A0, B0), 0.f);
    v.y = fmaxf(fmaf(v.y, A1, B1), 0.f);
    v.z = fmaxf(fmaf(v.z, A2, B2), 0.f);
    v.w = fmaxf(fmaf(v.w, A3, B3), 0.f);
    if (residual) {
        float4 h0 = *(const float4*)&hin[(size_t)i * 4];
        v.x += h0.x; v.y += h0.y; v.z += h0.z; v.w += h0.w;
    }
    *(float4*)&hout[(size_t)i * 4] = v;
}

// ---------------- Attention reductions ----------------
__global__ __launch_bounds__(256) void k_redmax(const float* __restrict__ a, float* __restrict__ pmax, int n) {
    float m = -3.4e38f;
    for (int i = blockIdx.x * blockDim.x + threadIdx.x; i < n; i += gridDim.x * blockDim.x)
        m = fmaxf(m, a[i]);
    __shared__ float s[256];
    s[threadIdx.x] = m;
    __syncthreads();
    for (int o = 128; o > 0; o >>= 1) {
        if (threadIdx.x < o) s[threadIdx.x] = fmaxf(s[threadIdx.x], s[threadIdx.x + o]);
        __syncthreads();
    }
    if (threadIdx.x == 0) pmax[blockIdx.x] = s[0];
}

// fused: per-block max of pmax[256] (redundant but uniform) then exp-sum
__global__ __launch_bounds__(256) void k_redsum(const float* __restrict__ a, const float* __restrict__ pmax,
                                                float* __restrict__ psum, int n) {
    __shared__ float s[256];
    int t = threadIdx.x;
    s[t] = pmax[t];
    __syncthreads();
    for (int o = 128; o > 0; o >>= 1) {
        if (t < o) s[t] = fmaxf(s[t], s[t + o]);
        __syncthreads();
    }
    float M = s[0];
    __syncthreads();
    float acc = 0.f;
    for (int i = blockIdx.x * blockDim.x + t; i < n; i += gridDim.x * blockDim.x)
        acc += expf(a[i] - M);
    s[t] = acc;
    __syncthreads();
    for (int o = 128; o > 0; o >>= 1) {
        if (t < o) s[t] += s[t + o];
        __syncthreads();
    }
    if (t == 0) psum[blockIdx.x] = s[0];
}

// ---------------- Pooling (batch sorted) ----------------
__global__ __launch_bounds__(256) void k_pool(const float* __restrict__ h, const float* __restrict__ apre,
                                              const int* __restrict__ batch, const float* __restrict__ pmax,
                                              float* __restrict__ pooled, float* __restrict__ counts, int n) {
    __shared__ float sm[256];
    int t = threadIdx.x;
    sm[t] = pmax[t];
    __syncthreads();
    for (int o = 128; o > 0; o >>= 1) {
        if (t < o) sm[t] = fmaxf(sm[t], sm[t + o]);
        __syncthreads();
    }
    float M = sm[0];
    int col = t & 127, sub = t >> 7;
    int rpb = (n + gridDim.x - 1) / gridDim.x;
    int r0 = blockIdx.x * rpb;
    int r1 = r0 + rpb; if (r1 > n) r1 = n;
    float acc = 0.f, cntf = 0.f;
    int cur = -1;
    for (int r = r0 + sub; r < r1; r += 2) {
        int g = batch[r];
        if (g != cur) {
            if (cur >= 0) {
                atomicAdd(&pooled[cur * HH + col], acc);
                if (col == 0) atomicAdd(&counts[cur], cntf);
            }
            cur = g; acc = 0.f; cntf = 0.f;
        }
        float s = expf(apre[r] - M);
        acc = fmaf(h[(size_t)r * HH + col], s, acc);
        cntf += 1.0f;
    }
    if (cur >= 0) {
        atomicAdd(&pooled[cur * HH + col], acc);
        if (col == 0) atomicAdd(&counts[cur], cntf);
    }
}

// ---------------- Final MLP (fused softmax-denominator reduce) ----------------
__global__ __launch_bounds__(128) void k_mlp(const float* __restrict__ pooled, const float* __restrict__ counts,
                                             const float* __restrict__ psum, const float* __restrict__ W1,
                                             const float* __restrict__ b1, const float* __restrict__ W2,
                                             const float* __restrict__ b2, float* __restrict__ out) {
    int g = blockIdx.x;
    int t = threadIdx.x;
    __shared__ float ss[128];
    __shared__ float p[128], t1[128];
    ss[t] = psum[t] + psum[t + 128];
    __syncthreads();
    for (int o = 64; o > 0; o >>= 1) {
        if (t < o) ss[t] += ss[t + o];
        __syncthreads();
    }
    float S = ss[0];
    float c = fmaxf(counts[g], 1.0f);
    p[t] = pooled[g * HH + t] / (S * c);
    __syncthreads();
    float acc = b1[t];
    for (int k = 0; k < 128; ++k) acc = fmaf(p[k], W1[k * HH + t], acc);
    t1[t] = fmaxf(acc, 0.f);
    __syncthreads();
    float acc2 = b2[t];
    for (int j = 0; j < 128; ++j) acc2 = fmaf(t1[j], W2[j * HH + t], acc2);
    out[g * HH + t] = acc2;
}

extern "C" void kernel_launch(void* const* d_in, const int* in_sizes, int n_in,
                              void* d_out, int out_size, void* d_ws, size_t ws_size,
                              hipStream_t stream) {
    const float* x       = (const float*)d_in[0];
    const int*   ei      = (const int*)d_in[1];
    const int*   batch   = (const int*)d_in[2];
    const float* conv_w  = (const float*)d_in[3];
    const float* conv_b  = (const float*)d_in[4];
    const float* bn_g    = (const float*)d_in[5];
    const float* bn_b    = (const float*)d_in[6];
    const float* attn_w1 = (const float*)d_in[7];
    const float* attn_b1 = (const float*)d_in[8];
    const float* attn_w2 = (const float*)d_in[9];
    const float* attn_b2 = (const float*)d_in[10];
    const float* proj_w1 = (const float*)d_in[11];
    const float* proj_b1 = (const float*)d_in[12];
    const float* proj_w2 = (const float*)d_in[13];
    const float* proj_b2 = (const float*)d_in[14];

    const int E = in_sizes[1] / 2;
    const int n = in_sizes[2];
    const int* srcp = ei;
    const int* dstp = ei + E;

    // ---- workspace layout ----
    char* base = (char*)d_ws;
    size_t off = 0;
    auto alloc = [&](size_t bytes) -> char* {
        char* p = base + off;
        off = (off + bytes + 511) & ~(size_t)511;
        return p;
    };
    int*   cntcur  = (int*)alloc((size_t)2 * n * 4);     // cnt | cursor (one memset)
    int*   cnt     = cntcur;
    int*   cursor  = cntcur + n;
    int*   rowptr  = (int*)alloc((size_t)(n + 1) * 4);
    int*   tmp     = (int*)alloc((size_t)n * 4);
    int*   bsum    = (int*)alloc(512 * 4);
    float* dinv    = (float*)alloc((size_t)n * 4);
    int2*  epk     = (int2*)alloc((size_t)E * 8);
    float* h       = (float*)alloc((size_t)n * HH * 4);
    float* z       = (float*)alloc((size_t)n * HH * 4);
    float* agg     = (float*)alloc((size_t)n * HH * 4);
    float* colsum  = (float*)alloc(512);                 // colsum | colsq contiguous
    float* colsq   = (float*)alloc(512);
    float* apre    = (float*)alloc((size_t)n * 4);
    float* pmax    = (float*)alloc(1024);
    float* psum    = (float*)alloc(1024);
    float* pooled  = (float*)alloc(GG * HH * 4 + 512);   // pooled | counts contiguous
    float* counts  = pooled + GG * HH;

    const int eGrid    = (E + 255) / 256;
    const int nGrid    = (n + 255) / 256;
    const int nbScan   = (n + 511) / 512;
    const int gemmGrid = (n + 63) / 64;
    const int waveGrid = (n + 3) / 4;
    const int bnGrid   = (n * (HH / 4) + 255) / 256;

    // ---- CSR build ----
    hipMemsetAsync(cntcur, 0, (size_t)2 * n * 4, stream);
    k_count<<<eGrid, 256, 0, stream>>>(dstp, cnt, E);
    k_scanA<<<nbScan, 512, 0, stream>>>(cnt, tmp, bsum, n);
    k_scanB<<<1, 512, 0, stream>>>(bsum, nbScan);
    k_scanC<<<nGrid, 256, 0, stream>>>(tmp, bsum, cnt, rowptr, dinv, n);
    k_fill<<<eGrid, 256, 0, stream>>>(srcp, dstp, rowptr, cursor, dinv, epk, E);

    // ---- GCN layers ----
    for (int l = 0; l < 3; ++l) {
        const float* A = (l == 0) ? x : h;
        k_gemm<0><<<gemmGrid, 256, 0, stream>>>(A, conv_w + (size_t)l * HH * HH, nullptr, z,
                                                nullptr, nullptr, n);
        k_agg<<<waveGrid, 256, 0, stream>>>(z, rowptr, epk, dinv, conv_b + l * HH, agg, n);
        hipMemsetAsync(colsum, 0, 1024, stream);
        k_bnstats<<<256, 256, 0, stream>>>(agg, colsum, colsq, n);
        k_bnapply<<<bnGrid, 256, 0, stream>>>(agg, colsum, colsq, bn_g + l * HH, bn_b + l * HH,
                                              h, h, n, (l > 0) ? 1 : 0);
    }

    // ---- attention (GEMV fused into GEMM epilogue) ----
    k_gemm<1><<<gemmGrid, 256, 0, stream>>>(h, attn_w1, attn_b1, apre, attn_w2, attn_b2, n);
    k_redmax<<<256, 256, 0, stream>>>(apre, pmax, n);
    k_redsum<<<256, 256, 0, stream>>>(apre, pmax, psum, n);

    // ---- pooling + MLP ----
    hipMemsetAsync(pooled, 0, GG * HH * 4 + 512, stream);
    k_pool<<<128, 256, 0, stream>>>(h, apre, batch, pmax, pooled, counts, n);
    k_mlp<<<GG, 128, 0, stream>>>(pooled, counts, psum, proj_w1, proj_b1, proj_w2, proj_b2,
                                  (float*)d_out);
}

// Round 5
// 1142.449 us; speedup vs baseline: 1.3356x; 1.1564x over previous
//
#include <hip/hip_runtime.h>

#define HH 128
#define GG 64
#define EPS 1e-5f

// ---------------- CSR build ----------------
__global__ void k_count(const int* __restrict__ dst, int* __restrict__ cnt, int E) {
    int i = blockIdx.x * blockDim.x + threadIdx.x;
    if (i < E) atomicAdd(&cnt[dst[i]], 1);
}

__global__ __launch_bounds__(512) void k_scanA(const int* __restrict__ cnt, int* __restrict__ tmp,
                                               int* __restrict__ bsum, int n) {
    __shared__ int s[512];
    int t = threadIdx.x;
    int i = blockIdx.x * 512 + t;
    s[t] = (i < n) ? cnt[i] : 0;
    __syncthreads();
    for (int o = 1; o < 512; o <<= 1) {
        int u = (t >= o) ? s[t - o] : 0;
        __syncthreads();
        s[t] += u;
        __syncthreads();
    }
    if (i < n) tmp[i] = s[t];
    if (t == 511) bsum[blockIdx.x] = s[511];
}

__global__ __launch_bounds__(512) void k_scanB(int* __restrict__ bsum, int nb) {
    __shared__ int s[512];
    int t = threadIdx.x;
    s[t] = (t < nb) ? bsum[t] : 0;
    __syncthreads();
    for (int o = 1; o < 512; o <<= 1) {
        int u = (t >= o) ? s[t - o] : 0;
        __syncthreads();
        s[t] += u;
        __syncthreads();
    }
    if (t < nb) bsum[t] = s[t];
}

// rowptr + dinv fused
__global__ void k_scanC(const int* __restrict__ tmp, const int* __restrict__ bsum,
                        const int* __restrict__ cnt, int* __restrict__ rowptr,
                        float* __restrict__ dinv, int n) {
    int i = blockIdx.x * blockDim.x + threadIdx.x;
    if (i < n) {
        int b = i >> 9;
        int off = (b > 0) ? bsum[b - 1] : 0;
        rowptr[i + 1] = tmp[i] + off;
        if (i == 0) rowptr[0] = 0;
        dinv[i] = rsqrtf((float)(cnt[i] + 1));
    }
}

// fill packed (col, norm) pairs
__global__ void k_fill(const int* __restrict__ src, const int* __restrict__ dst,
                       const int* __restrict__ rowptr, int* __restrict__ cursor,
                       const float* __restrict__ dinv, int2* __restrict__ epk, int E) {
    int e = blockIdx.x * blockDim.x + threadIdx.x;
    if (e < E) {
        int s0 = src[e], d0 = dst[e];
        int p = atomicAdd(&cursor[d0], 1);
        int idx = rowptr[d0] + p;
        epk[idx] = make_int2(s0, __float_as_int(dinv[s0] * dinv[d0]));
    }
}

// ---------------- GEMM: C[n x 128] = A[n x 128] @ W[128 x 128] ----------------
// ACT==0: C = A@W (raw).  ACT==1: apre[r] = tanh(A@W + b1) @ w2 + b2  (C is apre[n])
#define FMA_ROW(i, a)                       \
    acc[i][0] = fmaf(a, w0.x, acc[i][0]);   \
    acc[i][1] = fmaf(a, w0.y, acc[i][1]);   \
    acc[i][2] = fmaf(a, w0.z, acc[i][2]);   \
    acc[i][3] = fmaf(a, w0.w, acc[i][3]);   \
    acc[i][4] = fmaf(a, w1.x, acc[i][4]);   \
    acc[i][5] = fmaf(a, w1.y, acc[i][5]);   \
    acc[i][6] = fmaf(a, w1.z, acc[i][6]);   \
    acc[i][7] = fmaf(a, w1.w, acc[i][7]);

template <int ACT>
__global__ __launch_bounds__(256, 2) void k_gemm(const float* __restrict__ A, const float* __restrict__ W,
                                                 const float* __restrict__ bias, float* __restrict__ C,
                                                 const float* __restrict__ w2, const float* __restrict__ b2,
                                                 int n) {
    __shared__ float hl[64][128];   // A tile
    __shared__ float Ws[64][128];   // W k-chunk
    int tb = blockIdx.x * 64;
    int t = threadIdx.x;
    int rows = n - tb; if (rows > 64) rows = 64;
    for (int idx = t; idx < 64 * 32; idx += 256) {
        int r = idx >> 5, c4 = (idx & 31) << 2;
        if (r < rows)
            *(float4*)&hl[r][c4] = *(const float4*)&A[(size_t)(tb + r) * HH + c4];
    }
    int tx = t & 15;       // owns cols 8*tx..8*tx+7
    int ty = t >> 4;       // owns rows ty + 16*i
    int tx8 = tx << 3;
    float acc[4][8] = {};
    for (int kc = 0; kc < 2; ++kc) {
        __syncthreads();   // hl ready (kc=0) / previous chunk compute done (kc=1)
        for (int idx = t; idx < 64 * 32; idx += 256) {
            int r = idx >> 5, c4 = (idx & 31) << 2;
            *(float4*)&Ws[r][c4] = *(const float4*)&W[(size_t)(kc * 64 + r) * HH + c4];
        }
        __syncthreads();
        int kb = kc * 64;
        for (int k = 0; k < 64; ++k) {
            float4 w0 = *(const float4*)&Ws[k][tx8];
            float4 w1 = *(const float4*)&Ws[k][tx8 + 4];
            float a0 = hl[ty][kb + k];
            float a1 = hl[ty + 16][kb + k];
            float a2 = hl[ty + 32][kb + k];
            float a3 = hl[ty + 48][kb + k];
            FMA_ROW(0, a0)
            FMA_ROW(1, a1)
            FMA_ROW(2, a2)
            FMA_ROW(3, a3)
        }
    }
    if (ACT == 0) {
#pragma unroll
        for (int i = 0; i < 4; ++i) {
            int r = tb + ty + 16 * i;
            if (r < n) {
                float4 o0 = {acc[i][0], acc[i][1], acc[i][2], acc[i][3]};
                float4 o1 = {acc[i][4], acc[i][5], acc[i][6], acc[i][7]};
                *(float4*)&C[(size_t)r * HH + tx8] = o0;
                *(float4*)&C[(size_t)r * HH + tx8 + 4] = o1;
            }
        }
    } else {
        // fused attention GEMV: apre[r] = sum_c tanh(acc+b1[c]) * w2[c] + b2
        float b1v[8], w2v[8];
#pragma unroll
        for (int j = 0; j < 8; ++j) { b1v[j] = bias[tx8 + j]; w2v[j] = w2[tx8 + j]; }
        float b2s = b2[0];
#pragma unroll
        for (int i = 0; i < 4; ++i) {
            float s = 0.f;
#pragma unroll
            for (int j = 0; j < 8; ++j)
                s = fmaf(tanhf(acc[i][j] + b1v[j]), w2v[j], s);
            s += __shfl_xor(s, 1);
            s += __shfl_xor(s, 2);
            s += __shfl_xor(s, 4);
            s += __shfl_xor(s, 8);
            int r = tb + ty + 16 * i;
            if (tx == 0 && r < n) C[r] = s + b2s;
        }
    }
}

// ---------------- Aggregation ----------------
// wave = 1 node; two 32-lane halves process interleaved edges (4 in flight each);
// each lane holds float4 (4 cols); merge halves via shfl_xor(32).
// NOTE: macro params must not be named 'w'/'x'/'y'/'z' — they'd substitute into member accesses.
#define AGG_FMA(vv, ww)                                         \
    acc.x = fmaf(vv.x, ww, acc.x); acc.y = fmaf(vv.y, ww, acc.y); \
    acc.z = fmaf(vv.z, ww, acc.z); acc.w = fmaf(vv.w, ww, acc.w);

__global__ __launch_bounds__(256) void k_agg(const float* __restrict__ z, const int* __restrict__ rowptr,
                                             const int2* __restrict__ epk, const float* __restrict__ dinv,
                                             const float* __restrict__ bias, float* __restrict__ agg, int n) {
    int wid = (int)((blockIdx.x * (size_t)blockDim.x + threadIdx.x) >> 6);
    if (wid >= n) return;
    int lane = threadIdx.x & 63;
    int half = lane >> 5;
    int c0 = (lane & 31) << 2;
    int beg = rowptr[wid], end = rowptr[wid + 1];
    float4 acc = {0.f, 0.f, 0.f, 0.f};
    if (half == 0) {
        float di = dinv[wid];
        float ws = di * di;
        float4 zs = *(const float4*)&z[(size_t)wid * HH + c0];
        acc.x = zs.x * ws; acc.y = zs.y * ws; acc.z = zs.z * ws; acc.w = zs.w * ws;
    }
    int e = beg + half;
    for (; e + 6 < end; e += 8) {
        int2 p0 = epk[e];
        int2 p1 = epk[e + 2];
        int2 p2 = epk[e + 4];
        int2 p3 = epk[e + 6];
        float4 v0 = *(const float4*)&z[(size_t)p0.x * HH + c0];
        float4 v1 = *(const float4*)&z[(size_t)p1.x * HH + c0];
        float4 v2 = *(const float4*)&z[(size_t)p2.x * HH + c0];
        float4 v3 = *(const float4*)&z[(size_t)p3.x * HH + c0];
        float e0 = __int_as_float(p0.y);
        float e1 = __int_as_float(p1.y);
        float e2 = __int_as_float(p2.y);
        float e3 = __int_as_float(p3.y);
        AGG_FMA(v0, e0)
        AGG_FMA(v1, e1)
        AGG_FMA(v2, e2)
        AGG_FMA(v3, e3)
    }
    for (; e < end; e += 2) {
        int2 p0 = epk[e];
        float4 v0 = *(const float4*)&z[(size_t)p0.x * HH + c0];
        float e0 = __int_as_float(p0.y);
        AGG_FMA(v0, e0)
    }
    acc.x += __shfl_xor(acc.x, 32);
    acc.y += __shfl_xor(acc.y, 32);
    acc.z += __shfl_xor(acc.z, 32);
    acc.w += __shfl_xor(acc.w, 32);
    if (half == 0) {
        float4 b4 = *(const float4*)&bias[c0];
        acc.x += b4.x; acc.y += b4.y; acc.z += b4.z; acc.w += b4.w;
        *(float4*)&agg[(size_t)wid * HH + c0] = acc;
    }
}

// ---------------- BatchNorm ----------------
__global__ __launch_bounds__(256) void k_bnstats(const float* __restrict__ agg, float* __restrict__ colsum,
                                                 float* __restrict__ colsq, int n) {
    int t = threadIdx.x;
    int col = t & 127, sub = t >> 7;
    int rpb = (n + gridDim.x - 1) / gridDim.x;
    int r0 = blockIdx.x * rpb;
    int r1 = r0 + rpb; if (r1 > n) r1 = n;
    float s = 0.f, q = 0.f;
    for (int r = r0 + sub; r < r1; r += 2) {
        float v = agg[(size_t)r * HH + col];
        s += v;
        q = fmaf(v, v, q);
    }
    __shared__ float ls[256], lq[256];
    ls[t] = s; lq[t] = q;
    __syncthreads();
    if (t < 128) {
        atomicAdd(&colsum[col], ls[t] + ls[t + 128]);
        atomicAdd(&colsq[col], lq[t] + lq[t + 128]);
    }
}

// BN apply (+fused scale/shift computation) + ReLU + optional residual
__global__ void k_bnapply(const float* __restrict__ agg, const float* __restrict__ colsum,
                          const float* __restrict__ colsq, const float* __restrict__ g,
                          const float* __restrict__ b, const float* __restrict__ hin,
                          float* __restrict__ hout, int n, int residual) {
    int i = blockIdx.x * blockDim.x + threadIdx.x;
    int nvec4 = n * (HH / 4);
    if (i >= nvec4) return;
    int c = (i << 2) & 127;
    float4 cs = *(const float4*)&colsum[c];
    float4 cq = *(const float4*)&colsq[c];
    float4 gg = *(const float4*)&g[c];
    float4 bb = *(const float4*)&b[c];
    float inv_n = 1.0f / (float)n;
    float m0 = cs.x * inv_n, m1 = cs.y * inv_n, m2 = cs.z * inv_n, m3 = cs.w * inv_n;
    float A0 = rsqrtf(cq.x * inv_n - m0 * m0 + EPS) * gg.x;
    float A1 = rsqrtf(cq.y * inv_n - m1 * m1 + EPS) * gg.y;
    float A2 = rsqrtf(cq.z * inv_n - m2 * m2 + EPS) * gg.z;
    float A3 = rsqrtf(cq.w * inv_n - m3 * m3 + EPS) * gg.w;
    float B0 = bb.x - m0 * A0, B1 = bb.y - m1 * A1, B2 = bb.z - m2 * A2, B3 = bb.w - m3 * A3;
    float4 v = *(const float4*)&agg[(size_t)i * 4];
    v.x = fmaxf(fmaf(v.x, A0, B0), 0.f);
    v.y = fmaxf(fmaf(v.y, A1, B1), 0.f);
    v.z = fmaxf(fmaf(v.z, A2, B2), 0.f);
    v.w = fmaxf(fmaf(v.w, A3, B3), 0.f);
    if (residual) {
        float4 h0 = *(const float4*)&hin[(size_t)i * 4];
        v.x += h0.x; v.y += h0.y; v.z += h0.z; v.w += h0.w;
    }
    *(float4*)&hout[(size_t)i * 4] = v;
}

// ---------------- Attention reductions ----------------
__global__ __launch_bounds__(256) void k_redmax(const float* __restrict__ a, float* __restrict__ pmax, int n) {
    float m = -3.4e38f;
    for (int i = blockIdx.x * blockDim.x + threadIdx.x; i < n; i += gridDim.x * blockDim.x)
        m = fmaxf(m, a[i]);
    __shared__ float s[256];
    s[threadIdx.x] = m;
    __syncthreads();
    for (int o = 128; o > 0; o >>= 1) {
        if (threadIdx.x < o) s[threadIdx.x] = fmaxf(s[threadIdx.x], s[threadIdx.x + o]);
        __syncthreads();
    }
    if (threadIdx.x == 0) pmax[blockIdx.x] = s[0];
}

// fused: per-block max of pmax[256] (redundant but uniform) then exp-sum
__global__ __launch_bounds__(256) void k_redsum(const float* __restrict__ a, const float* __restrict__ pmax,
                                                float* __restrict__ psum, int n) {
    __shared__ float s[256];
    int t = threadIdx.x;
    s[t] = pmax[t];
    __syncthreads();
    for (int o = 128; o > 0; o >>= 1) {
        if (t < o) s[t] = fmaxf(s[t], s[t + o]);
        __syncthreads();
    }
    float M = s[0];
    __syncthreads();
    float acc = 0.f;
    for (int i = blockIdx.x * blockDim.x + t; i < n; i += gridDim.x * blockDim.x)
        acc += expf(a[i] - M);
    s[t] = acc;
    __syncthreads();
    for (int o = 128; o > 0; o >>= 1) {
        if (t < o) s[t] += s[t + o];
        __syncthreads();
    }
    if (t == 0) psum[blockIdx.x] = s[0];
}

// ---------------- Pooling (batch sorted) ----------------
__global__ __launch_bounds__(256) void k_pool(const float* __restrict__ h, const float* __restrict__ apre,
                                              const int* __restrict__ batch, const float* __restrict__ pmax,
                                              float* __restrict__ pooled, float* __restrict__ counts, int n) {
    __shared__ float sm[256];
    int t = threadIdx.x;
    sm[t] = pmax[t];
    __syncthreads();
    for (int o = 128; o > 0; o >>= 1) {
        if (t < o) sm[t] = fmaxf(sm[t], sm[t + o]);
        __syncthreads();
    }
    float M = sm[0];
    int col = t & 127, sub = t >> 7;
    int rpb = (n + gridDim.x - 1) / gridDim.x;
    int r0 = blockIdx.x * rpb;
    int r1 = r0 + rpb; if (r1 > n) r1 = n;
    float acc = 0.f, cntf = 0.f;
    int cur = -1;
    for (int r = r0 + sub; r < r1; r += 2) {
        int g = batch[r];
        if (g != cur) {
            if (cur >= 0) {
                atomicAdd(&pooled[cur * HH + col], acc);
                if (col == 0) atomicAdd(&counts[cur], cntf);
            }
            cur = g; acc = 0.f; cntf = 0.f;
        }
        float s = expf(apre[r] - M);
        acc = fmaf(h[(size_t)r * HH + col], s, acc);
        cntf += 1.0f;
    }
    if (cur >= 0) {
        atomicAdd(&pooled[cur * HH + col], acc);
        if (col == 0) atomicAdd(&counts[cur], cntf);
    }
}

// ---------------- Final MLP (fused softmax-denominator reduce) ----------------
__global__ __launch_bounds__(128) void k_mlp(const float* __restrict__ pooled, const float* __restrict__ counts,
                                             const float* __restrict__ psum, const float* __restrict__ W1,
                                             const float* __restrict__ b1, const float* __restrict__ W2,
                                             const float* __restrict__ b2, float* __restrict__ out) {
    int g = blockIdx.x;
    int t = threadIdx.x;
    __shared__ float ss[128];
    __shared__ float p[128], t1[128];
    ss[t] = psum[t] + psum[t + 128];
    __syncthreads();
    for (int o = 64; o > 0; o >>= 1) {
        if (t < o) ss[t] += ss[t + o];
        __syncthreads();
    }
    float S = ss[0];
    float c = fmaxf(counts[g], 1.0f);
    p[t] = pooled[g * HH + t] / (S * c);
    __syncthreads();
    float acc = b1[t];
    for (int k = 0; k < 128; ++k) acc = fmaf(p[k], W1[k * HH + t], acc);
    t1[t] = fmaxf(acc, 0.f);
    __syncthreads();
    float acc2 = b2[t];
    for (int j = 0; j < 128; ++j) acc2 = fmaf(t1[j], W2[j * HH + t], acc2);
    out[g * HH + t] = acc2;
}

extern "C" void kernel_launch(void* const* d_in, const int* in_sizes, int n_in,
                              void* d_out, int out_size, void* d_ws, size_t ws_size,
                              hipStream_t stream) {
    const float* x       = (const float*)d_in[0];
    const int*   ei      = (const int*)d_in[1];
    const int*   batch   = (const int*)d_in[2];
    const float* conv_w  = (const float*)d_in[3];
    const float* conv_b  = (const float*)d_in[4];
    const float* bn_g    = (const float*)d_in[5];
    const float* bn_b    = (const float*)d_in[6];
    const float* attn_w1 = (const float*)d_in[7];
    const float* attn_b1 = (const float*)d_in[8];
    const float* attn_w2 = (const float*)d_in[9];
    const float* attn_b2 = (const float*)d_in[10];
    const float* proj_w1 = (const float*)d_in[11];
    const float* proj_b1 = (const float*)d_in[12];
    const float* proj_w2 = (const float*)d_in[13];
    const float* proj_b2 = (const float*)d_in[14];

    const int E = in_sizes[1] / 2;
    const int n = in_sizes[2];
    const int* srcp = ei;
    const int* dstp = ei + E;

    // ---- workspace layout ----
    char* base = (char*)d_ws;
    size_t off = 0;
    auto alloc = [&](size_t bytes) -> char* {
        char* p = base + off;
        off = (off + bytes + 511) & ~(size_t)511;
        return p;
    };
    int*   cntcur  = (int*)alloc((size_t)2 * n * 4);     // cnt | cursor (one memset)
    int*   cnt     = cntcur;
    int*   cursor  = cntcur + n;
    int*   rowptr  = (int*)alloc((size_t)(n + 1) * 4);
    int*   tmp     = (int*)alloc((size_t)n * 4);
    int*   bsum    = (int*)alloc(512 * 4);
    float* dinv    = (float*)alloc((size_t)n * 4);
    int2*  epk     = (int2*)alloc((size_t)E * 8);
    float* h       = (float*)alloc((size_t)n * HH * 4);
    float* z       = (float*)alloc((size_t)n * HH * 4);
    float* agg     = (float*)alloc((size_t)n * HH * 4);
    float* colsum  = (float*)alloc(512);                 // colsum | colsq contiguous
    float* colsq   = (float*)alloc(512);
    float* apre    = (float*)alloc((size_t)n * 4);
    float* pmax    = (float*)alloc(1024);
    float* psum    = (float*)alloc(1024);
    float* pooled  = (float*)alloc(GG * HH * 4 + 512);   // pooled | counts contiguous
    float* counts  = pooled + GG * HH;

    const int eGrid    = (E + 255) / 256;
    const int nGrid    = (n + 255) / 256;
    const int nbScan   = (n + 511) / 512;
    const int gemmGrid = (n + 63) / 64;
    const int waveGrid = (n + 3) / 4;
    const int bnGrid   = (n * (HH / 4) + 255) / 256;

    // ---- CSR build ----
    hipMemsetAsync(cntcur, 0, (size_t)2 * n * 4, stream);
    k_count<<<eGrid, 256, 0, stream>>>(dstp, cnt, E);
    k_scanA<<<nbScan, 512, 0, stream>>>(cnt, tmp, bsum, n);
    k_scanB<<<1, 512, 0, stream>>>(bsum, nbScan);
    k_scanC<<<nGrid, 256, 0, stream>>>(tmp, bsum, cnt, rowptr, dinv, n);
    k_fill<<<eGrid, 256, 0, stream>>>(srcp, dstp, rowptr, cursor, dinv, epk, E);

    // ---- GCN layers ----
    for (int l = 0; l < 3; ++l) {
        const float* A = (l == 0) ? x : h;
        k_gemm<0><<<gemmGrid, 256, 0, stream>>>(A, conv_w + (size_t)l * HH * HH, nullptr, z,
                                                nullptr, nullptr, n);
        k_agg<<<waveGrid, 256, 0, stream>>>(z, rowptr, epk, dinv, conv_b + l * HH, agg, n);
        hipMemsetAsync(colsum, 0, 1024, stream);
        k_bnstats<<<1024, 256, 0, stream>>>(agg, colsum, colsq, n);
        k_bnapply<<<bnGrid, 256, 0, stream>>>(agg, colsum, colsq, bn_g + l * HH, bn_b + l * HH,
                                              h, h, n, (l > 0) ? 1 : 0);
    }

    // ---- attention (GEMV fused into GEMM epilogue) ----
    k_gemm<1><<<gemmGrid, 256, 0, stream>>>(h, attn_w1, attn_b1, apre, attn_w2, attn_b2, n);
    k_redmax<<<256, 256, 0, stream>>>(apre, pmax, n);
    k_redsum<<<256, 256, 0, stream>>>(apre, pmax, psum, n);

    // ---- pooling + MLP ----
    hipMemsetAsync(pooled, 0, GG * HH * 4 + 512, stream);
    k_pool<<<1024, 256, 0, stream>>>(h, apre, batch, pmax, pooled, counts, n);
    k_mlp<<<GG, 128, 0, stream>>>(pooled, counts, psum, proj_w1, proj_b1, proj_w2, proj_b2,
                                  (float*)d_out);
}

// Round 6
// 1121.394 us; speedup vs baseline: 1.3607x; 1.0188x over previous
//
#include <hip/hip_runtime.h>

#define HH 128
#define GG 64
#define EPS 1e-5f

// monotonic float <-> uint mapping for atomicMax on floats of any sign
__device__ __forceinline__ unsigned femax_enc(float f) {
    unsigned u = __float_as_uint(f);
    return (u & 0x80000000u) ? ~u : (u | 0x80000000u);
}
__device__ __forceinline__ float femax_dec(unsigned u) {
    return (u & 0x80000000u) ? __uint_as_float(u & 0x7FFFFFFFu) : __uint_as_float(~u);
}

// ---------------- CSR build ----------------
__global__ void k_count(const int* __restrict__ dst, int* __restrict__ cnt, int E) {
    int i = blockIdx.x * blockDim.x + threadIdx.x;
    if (i < E) atomicAdd(&cnt[dst[i]], 1);
}

__global__ __launch_bounds__(512) void k_scanA(const int* __restrict__ cnt, int* __restrict__ tmp,
                                               int* __restrict__ bsum, int n) {
    __shared__ int s[512];
    int t = threadIdx.x;
    int i = blockIdx.x * 512 + t;
    s[t] = (i < n) ? cnt[i] : 0;
    __syncthreads();
    for (int o = 1; o < 512; o <<= 1) {
        int u = (t >= o) ? s[t - o] : 0;
        __syncthreads();
        s[t] += u;
        __syncthreads();
    }
    if (i < n) tmp[i] = s[t];
    if (t == 511) bsum[blockIdx.x] = s[511];
}

__global__ __launch_bounds__(512) void k_scanB(int* __restrict__ bsum, int nb) {
    __shared__ int s[512];
    int t = threadIdx.x;
    s[t] = (t < nb) ? bsum[t] : 0;
    __syncthreads();
    for (int o = 1; o < 512; o <<= 1) {
        int u = (t >= o) ? s[t - o] : 0;
        __syncthreads();
        s[t] += u;
        __syncthreads();
    }
    if (t < nb) bsum[t] = s[t];
}

// rowptr + dinv fused
__global__ void k_scanC(const int* __restrict__ tmp, const int* __restrict__ bsum,
                        const int* __restrict__ cnt, int* __restrict__ rowptr,
                        float* __restrict__ dinv, int n) {
    int i = blockIdx.x * blockDim.x + threadIdx.x;
    if (i < n) {
        int b = i >> 9;
        int off = (b > 0) ? bsum[b - 1] : 0;
        rowptr[i + 1] = tmp[i] + off;
        if (i == 0) rowptr[0] = 0;
        dinv[i] = rsqrtf((float)(cnt[i] + 1));
    }
}

// fill packed (col, norm) pairs
__global__ void k_fill(const int* __restrict__ src, const int* __restrict__ dst,
                       const int* __restrict__ rowptr, int* __restrict__ cursor,
                       const float* __restrict__ dinv, int2* __restrict__ epk, int E) {
    int e = blockIdx.x * blockDim.x + threadIdx.x;
    if (e < E) {
        int s0 = src[e], d0 = dst[e];
        int p = atomicAdd(&cursor[d0], 1);
        int idx = rowptr[d0] + p;
        epk[idx] = make_int2(s0, __float_as_int(dinv[s0] * dinv[d0]));
    }
}

// ---------------- GEMM: C[n x 128] = A[n x 128] @ W[128 x 128] ----------------
// ACT==0: C = A@W.  ACT==1: apre[r] = tanh(A@W + b1) @ w2 + b2, and atomicMax block max -> gmax
#define FMA_ROW(i, a)                       \
    acc[i][0] = fmaf(a, w0.x, acc[i][0]);   \
    acc[i][1] = fmaf(a, w0.y, acc[i][1]);   \
    acc[i][2] = fmaf(a, w0.z, acc[i][2]);   \
    acc[i][3] = fmaf(a, w0.w, acc[i][3]);   \
    acc[i][4] = fmaf(a, w1.x, acc[i][4]);   \
    acc[i][5] = fmaf(a, w1.y, acc[i][5]);   \
    acc[i][6] = fmaf(a, w1.z, acc[i][6]);   \
    acc[i][7] = fmaf(a, w1.w, acc[i][7]);

template <int ACT>
__global__ __launch_bounds__(256, 2) void k_gemm(const float* __restrict__ A, const float* __restrict__ W,
                                                 const float* __restrict__ bias, float* __restrict__ C,
                                                 const float* __restrict__ w2, const float* __restrict__ b2,
                                                 unsigned* __restrict__ gmax, int n) {
    // hl padded to 132 floats/row: A-column reads hl[ty+16i][k] land on banks (4*ty+k)%32
    // instead of all aliasing bank k%32 (row stride 512B) -> kills a 4-way conflict.
    __shared__ float hl[64][132];
    __shared__ float Ws[64][128];
    int tb = blockIdx.x * 64;
    int t = threadIdx.x;
    int rows = n - tb; if (rows > 64) rows = 64;
    for (int idx = t; idx < 64 * 32; idx += 256) {
        int r = idx >> 5, c4 = (idx & 31) << 2;
        if (r < rows)
            *(float4*)&hl[r][c4] = *(const float4*)&A[(size_t)(tb + r) * HH + c4];
    }
    int tx = t & 15;       // owns cols 8*tx..8*tx+7
    int ty = t >> 4;       // owns rows ty + 16*i
    int tx8 = tx << 3;
    float acc[4][8] = {};
    for (int kc = 0; kc < 2; ++kc) {
        __syncthreads();
        for (int idx = t; idx < 64 * 32; idx += 256) {
            int r = idx >> 5, c4 = (idx & 31) << 2;
            *(float4*)&Ws[r][c4] = *(const float4*)&W[(size_t)(kc * 64 + r) * HH + c4];
        }
        __syncthreads();
        int kb = kc * 64;
        for (int k = 0; k < 64; ++k) {
            float4 w0 = *(const float4*)&Ws[k][tx8];
            float4 w1 = *(const float4*)&Ws[k][tx8 + 4];
            float a0 = hl[ty][kb + k];
            float a1 = hl[ty + 16][kb + k];
            float a2 = hl[ty + 32][kb + k];
            float a3 = hl[ty + 48][kb + k];
            FMA_ROW(0, a0)
            FMA_ROW(1, a1)
            FMA_ROW(2, a2)
            FMA_ROW(3, a3)
        }
    }
    if (ACT == 0) {
#pragma unroll
        for (int i = 0; i < 4; ++i) {
            int r = tb + ty + 16 * i;
            if (r < n) {
                float4 o0 = {acc[i][0], acc[i][1], acc[i][2], acc[i][3]};
                float4 o1 = {acc[i][4], acc[i][5], acc[i][6], acc[i][7]};
                *(float4*)&C[(size_t)r * HH + tx8] = o0;
                *(float4*)&C[(size_t)r * HH + tx8 + 4] = o1;
            }
        }
    } else {
        // fused attention GEMV: apre[r] = sum_c tanh(acc+b1[c]) * w2[c] + b2; track block max
        float b1v[8], w2v[8];
#pragma unroll
        for (int j = 0; j < 8; ++j) { b1v[j] = bias[tx8 + j]; w2v[j] = w2[tx8 + j]; }
        float b2s = b2[0];
        float lmax = -3.4e38f;
#pragma unroll
        for (int i = 0; i < 4; ++i) {
            float s = 0.f;
#pragma unroll
            for (int j = 0; j < 8; ++j)
                s = fmaf(tanhf(acc[i][j] + b1v[j]), w2v[j], s);
            s += __shfl_xor(s, 1);
            s += __shfl_xor(s, 2);
            s += __shfl_xor(s, 4);
            s += __shfl_xor(s, 8);
            int r = tb + ty + 16 * i;
            float val = s + b2s;
            if (r < n) {
                lmax = fmaxf(lmax, val);
                if (tx == 0) C[r] = val;
            }
        }
        // block max -> one atomicMax per block
        lmax = fmaxf(lmax, __shfl_xor(lmax, 16));
        lmax = fmaxf(lmax, __shfl_xor(lmax, 32));
        __shared__ float wm[4];
        if ((t & 63) == 0) wm[t >> 6] = lmax;
        __syncthreads();
        if (t == 0) {
            float m = fmaxf(fmaxf(wm[0], wm[1]), fmaxf(wm[2], wm[3]));
            atomicMax(gmax, femax_enc(m));
        }
    }
}

// ---------------- Aggregation ----------------
// wave = 1 node; two 32-lane halves process interleaved edges, predicated unroll-8
// (8 gathers in flight per half, no serial tail); lanes hold float4 (4 cols);
// halves merged via shfl_xor(32).
#define AGG_FMA(vv, ww)                                           \
    acc.x = fmaf(vv.x, ww, acc.x); acc.y = fmaf(vv.y, ww, acc.y); \
    acc.z = fmaf(vv.z, ww, acc.z); acc.w = fmaf(vv.w, ww, acc.w);

__global__ __launch_bounds__(256) void k_agg(const float* __restrict__ z, const int* __restrict__ rowptr,
                                             const int2* __restrict__ epk, const float* __restrict__ dinv,
                                             const float* __restrict__ bias, float* __restrict__ agg, int n) {
    int wid = (int)((blockIdx.x * (size_t)blockDim.x + threadIdx.x) >> 6);
    if (wid >= n) return;
    int lane = threadIdx.x & 63;
    int half = lane >> 5;
    int c0 = (lane & 31) << 2;
    int beg = rowptr[wid], end = rowptr[wid + 1];
    float4 acc = {0.f, 0.f, 0.f, 0.f};
    if (half == 0) {
        float di = dinv[wid];
        float ws = di * di;
        float4 zs = *(const float4*)&z[(size_t)wid * HH + c0];
        acc.x = zs.x * ws; acc.y = zs.y * ws; acc.z = zs.z * ws; acc.w = zs.w * ws;
    }
    for (int e = beg + half; e < end; e += 16) {
        int2 p[8];
        float w[8];
#pragma unroll
        for (int j = 0; j < 8; ++j) {
            int idx = e + 2 * j;
            bool valid = idx < end;
            p[j] = epk[valid ? idx : beg];          // dummy -> epk[beg] (L1-hot), weight 0
            w[j] = valid ? __int_as_float(p[j].y) : 0.f;
        }
        float4 v[8];
#pragma unroll
        for (int j = 0; j < 8; ++j)
            v[j] = *(const float4*)&z[(size_t)p[j].x * HH + c0];
#pragma unroll
        for (int j = 0; j < 8; ++j) { AGG_FMA(v[j], w[j]) }
    }
    acc.x += __shfl_xor(acc.x, 32);
    acc.y += __shfl_xor(acc.y, 32);
    acc.z += __shfl_xor(acc.z, 32);
    acc.w += __shfl_xor(acc.w, 32);
    if (half == 0) {
        float4 b4 = *(const float4*)&bias[c0];
        acc.x += b4.x; acc.y += b4.y; acc.z += b4.z; acc.w += b4.w;
        *(float4*)&agg[(size_t)wid * HH + c0] = acc;
    }
}

// ---------------- BatchNorm ----------------
__global__ __launch_bounds__(256) void k_bnstats(const float* __restrict__ agg, float* __restrict__ colsum,
                                                 float* __restrict__ colsq, int n) {
    int t = threadIdx.x;
    int col = t & 127, sub = t >> 7;
    int rpb = (n + gridDim.x - 1) / gridDim.x;
    int r0 = blockIdx.x * rpb;
    int r1 = r0 + rpb; if (r1 > n) r1 = n;
    float s = 0.f, q = 0.f;
    for (int r = r0 + sub; r < r1; r += 2) {
        float v = agg[(size_t)r * HH + col];
        s += v;
        q = fmaf(v, v, q);
    }
    __shared__ float ls[256], lq[256];
    ls[t] = s; lq[t] = q;
    __syncthreads();
    if (t < 128) {
        atomicAdd(&colsum[col], ls[t] + ls[t + 128]);
        atomicAdd(&colsq[col], lq[t] + lq[t + 128]);
    }
}

// BN apply (+fused scale/shift computation) + ReLU + optional residual
__global__ void k_bnapply(const float* __restrict__ agg, const float* __restrict__ colsum,
                          const float* __restrict__ colsq, const float* __restrict__ g,
                          const float* __restrict__ b, const float* __restrict__ hin,
                          float* __restrict__ hout, int n, int residual) {
    int i = blockIdx.x * blockDim.x + threadIdx.x;
    int nvec4 = n * (HH / 4);
    if (i >= nvec4) return;
    int c = (i << 2) & 127;
    float4 cs = *(const float4*)&colsum[c];
    float4 cq = *(const float4*)&colsq[c];
    float4 gg = *(const float4*)&g[c];
    float4 bb = *(const float4*)&b[c];
    float inv_n = 1.0f / (float)n;
    float m0 = cs.x * inv_n, m1 = cs.y * inv_n, m2 = cs.z * inv_n, m3 = cs.w * inv_n;
    float A0 = rsqrtf(cq.x * inv_n - m0 * m0 + EPS) * gg.x;
    float A1 = rsqrtf(cq.y * inv_n - m1 * m1 + EPS) * gg.y;
    float A2 = rsqrtf(cq.z * inv_n - m2 * m2 + EPS) * gg.z;
    float A3 = rsqrtf(cq.w * inv_n - m3 * m3 + EPS) * gg.w;
    float B0 = bb.x - m0 * A0, B1 = bb.y - m1 * A1, B2 = bb.z - m2 * A2, B3 = bb.w - m3 * A3;
    float4 v = *(const float4*)&agg[(size_t)i * 4];
    v.x = fmaxf(fmaf(v.x, A0, B0), 0.f);
    v.y = fmaxf(fmaf(v.y, A1, B1), 0.f);
    v.z = fmaxf(fmaf(v.z, A2, B2), 0.f);
    v.w = fmaxf(fmaf(v.w, A3, B3), 0.f);
    if (residual) {
        float4 h0 = *(const float4*)&hin[(size_t)i * 4];
        v.x += h0.x; v.y += h0.y; v.z += h0.z; v.w += h0.w;
    }
    *(float4*)&hout[(size_t)i * 4] = v;
}

// ---------------- Attention denominator (max comes from fused gemm epilogue) ----------------
__global__ __launch_bounds__(256) void k_redsum(const float* __restrict__ a, const unsigned* __restrict__ gmax,
                                                float* __restrict__ psum, int n) {
    float M = femax_dec(*gmax);
    float acc = 0.f;
    for (int i = blockIdx.x * blockDim.x + threadIdx.x; i < n; i += gridDim.x * blockDim.x)
        acc += expf(a[i] - M);
    __shared__ float s[256];
    s[threadIdx.x] = acc;
    __syncthreads();
    for (int o = 128; o > 0; o >>= 1) {
        if (threadIdx.x < o) s[threadIdx.x] += s[threadIdx.x + o];
        __syncthreads();
    }
    if (threadIdx.x == 0) psum[blockIdx.x] = s[0];
}

// ---------------- Pooling (batch sorted) ----------------
__global__ __launch_bounds__(256) void k_pool(const float* __restrict__ h, const float* __restrict__ apre,
                                              const int* __restrict__ batch, const unsigned* __restrict__ gmax,
                                              float* __restrict__ pooled, float* __restrict__ counts, int n) {
    float M = femax_dec(*gmax);
    int t = threadIdx.x;
    int col = t & 127, sub = t >> 7;
    int rpb = (n + gridDim.x - 1) / gridDim.x;
    int r0 = blockIdx.x * rpb;
    int r1 = r0 + rpb; if (r1 > n) r1 = n;
    float acc = 0.f, cntf = 0.f;
    int cur = -1;
    for (int r = r0 + sub; r < r1; r += 2) {
        int g = batch[r];
        if (g != cur) {
            if (cur >= 0) {
                atomicAdd(&pooled[cur * HH + col], acc);
                if (col == 0) atomicAdd(&counts[cur], cntf);
            }
            cur = g; acc = 0.f; cntf = 0.f;
        }
        float s = expf(apre[r] - M);
        acc = fmaf(h[(size_t)r * HH + col], s, acc);
        cntf += 1.0f;
    }
    if (cur >= 0) {
        atomicAdd(&pooled[cur * HH + col], acc);
        if (col == 0) atomicAdd(&counts[cur], cntf);
    }
}

// ---------------- Final MLP (fused softmax-denominator reduce) ----------------
__global__ __launch_bounds__(128) void k_mlp(const float* __restrict__ pooled, const float* __restrict__ counts,
                                             const float* __restrict__ psum, const float* __restrict__ W1,
                                             const float* __restrict__ b1, const float* __restrict__ W2,
                                             const float* __restrict__ b2, float* __restrict__ out) {
    int g = blockIdx.x;
    int t = threadIdx.x;
    __shared__ float ss[128];
    __shared__ float p[128], t1[128];
    ss[t] = psum[t] + psum[t + 128];
    __syncthreads();
    for (int o = 64; o > 0; o >>= 1) {
        if (t < o) ss[t] += ss[t + o];
        __syncthreads();
    }
    float S = ss[0];
    float c = fmaxf(counts[g], 1.0f);
    p[t] = pooled[g * HH + t] / (S * c);
    __syncthreads();
    float acc = b1[t];
    for (int k = 0; k < 128; ++k) acc = fmaf(p[k], W1[k * HH + t], acc);
    t1[t] = fmaxf(acc, 0.f);
    __syncthreads();
    float acc2 = b2[t];
    for (int j = 0; j < 128; ++j) acc2 = fmaf(t1[j], W2[j * HH + t], acc2);
    out[g * HH + t] = acc2;
}

extern "C" void kernel_launch(void* const* d_in, const int* in_sizes, int n_in,
                              void* d_out, int out_size, void* d_ws, size_t ws_size,
                              hipStream_t stream) {
    const float* x       = (const float*)d_in[0];
    const int*   ei      = (const int*)d_in[1];
    const int*   batch   = (const int*)d_in[2];
    const float* conv_w  = (const float*)d_in[3];
    const float* conv_b  = (const float*)d_in[4];
    const float* bn_g    = (const float*)d_in[5];
    const float* bn_b    = (const float*)d_in[6];
    const float* attn_w1 = (const float*)d_in[7];
    const float* attn_b1 = (const float*)d_in[8];
    const float* attn_w2 = (const float*)d_in[9];
    const float* attn_b2 = (const float*)d_in[10];
    const float* proj_w1 = (const float*)d_in[11];
    const float* proj_b1 = (const float*)d_in[12];
    const float* proj_w2 = (const float*)d_in[13];
    const float* proj_b2 = (const float*)d_in[14];

    const int E = in_sizes[1] / 2;
    const int n = in_sizes[2];
    const int* srcp = ei;
    const int* dstp = ei + E;

    // ---- workspace layout ----
    char* base = (char*)d_ws;
    size_t off = 0;
    auto alloc = [&](size_t bytes) -> char* {
        char* p = base + off;
        off = (off + bytes + 511) & ~(size_t)511;
        return p;
    };
    int*   cntcur  = (int*)alloc((size_t)2 * n * 4);     // cnt | cursor (one memset)
    int*   cnt     = cntcur;
    int*   cursor  = cntcur + n;
    int*   rowptr  = (int*)alloc((size_t)(n + 1) * 4);
    int*   tmp     = (int*)alloc((size_t)n * 4);
    int*   bsum    = (int*)alloc(512 * 4);
    float* dinv    = (float*)alloc((size_t)n * 4);
    int2*  epk     = (int2*)alloc((size_t)E * 8);
    float* h       = (float*)alloc((size_t)n * HH * 4);
    float* z       = (float*)alloc((size_t)n * HH * 4);
    float* agg     = (float*)alloc((size_t)n * HH * 4);
    float* colsum  = (float*)alloc(512);                 // colsum | colsq contiguous
    float* colsq   = (float*)alloc(512);
    float* apre    = (float*)alloc((size_t)n * 4);
    unsigned* gmaxu = (unsigned*)alloc(512);
    float* psum    = (float*)alloc(1024);
    float* pooled  = (float*)alloc(GG * HH * 4 + 512);   // pooled | counts contiguous
    float* counts  = pooled + GG * HH;

    const int eGrid    = (E + 255) / 256;
    const int nGrid    = (n + 255) / 256;
    const int nbScan   = (n + 511) / 512;
    const int gemmGrid = (n + 63) / 64;
    const int waveGrid = (n + 3) / 4;
    const int bnGrid   = (n * (HH / 4) + 255) / 256;

    // ---- CSR build ----
    hipMemsetAsync(cntcur, 0, (size_t)2 * n * 4, stream);
    k_count<<<eGrid, 256, 0, stream>>>(dstp, cnt, E);
    k_scanA<<<nbScan, 512, 0, stream>>>(cnt, tmp, bsum, n);
    k_scanB<<<1, 512, 0, stream>>>(bsum, nbScan);
    k_scanC<<<nGrid, 256, 0, stream>>>(tmp, bsum, cnt, rowptr, dinv, n);
    k_fill<<<eGrid, 256, 0, stream>>>(srcp, dstp, rowptr, cursor, dinv, epk, E);

    // ---- GCN layers ----
    for (int l = 0; l < 3; ++l) {
        const float* A = (l == 0) ? x : h;
        k_gemm<0><<<gemmGrid, 256, 0, stream>>>(A, conv_w + (size_t)l * HH * HH, nullptr, z,
                                                nullptr, nullptr, nullptr, n);
        k_agg<<<waveGrid, 256, 0, stream>>>(z, rowptr, epk, dinv, conv_b + l * HH, agg, n);
        hipMemsetAsync(colsum, 0, 1024, stream);
        k_bnstats<<<1024, 256, 0, stream>>>(agg, colsum, colsq, n);
        k_bnapply<<<bnGrid, 256, 0, stream>>>(agg, colsum, colsq, bn_g + l * HH, bn_b + l * HH,
                                              h, h, n, (l > 0) ? 1 : 0);
    }

    // ---- attention (GEMV + max fused into GEMM epilogue) ----
    hipMemsetAsync(gmaxu, 0, 4, stream);
    k_gemm<1><<<gemmGrid, 256, 0, stream>>>(h, attn_w1, attn_b1, apre, attn_w2, attn_b2, gmaxu, n);
    k_redsum<<<256, 256, 0, stream>>>(apre, gmaxu, psum, n);

    // ---- pooling + MLP ----
    hipMemsetAsync(pooled, 0, GG * HH * 4 + 512, stream);
    k_pool<<<1024, 256, 0, stream>>>(h, apre, batch, gmaxu, pooled, counts, n);
    k_mlp<<<GG, 128, 0, stream>>>(pooled, counts, psum, proj_w1, proj_b1, proj_w2, proj_b2,
                                  (float*)d_out);
}

// Round 7
// 1080.657 us; speedup vs baseline: 1.4120x; 1.0377x over previous
//
#include <hip/hip_runtime.h>

#define HH 128
#define GG 64
#define EPS 1e-5f

// monotonic float <-> uint mapping for atomicMax on floats of any sign
__device__ __forceinline__ unsigned femax_enc(float f) {
    unsigned u = __float_as_uint(f);
    return (u & 0x80000000u) ? ~u : (u | 0x80000000u);
}
__device__ __forceinline__ float femax_dec(unsigned u) {
    return (u & 0x80000000u) ? __uint_as_float(u & 0x7FFFFFFFu) : __uint_as_float(~u);
}

// ---------------- CSR build ----------------
__global__ void k_count(const int* __restrict__ dst, int* __restrict__ cnt, int E) {
    int i = blockIdx.x * blockDim.x + threadIdx.x;
    if (i < E) atomicAdd(&cnt[dst[i]], 1);
}

__global__ __launch_bounds__(512) void k_scanA(const int* __restrict__ cnt, int* __restrict__ tmp,
                                               int* __restrict__ bsum, int n) {
    __shared__ int s[512];
    int t = threadIdx.x;
    int i = blockIdx.x * 512 + t;
    s[t] = (i < n) ? cnt[i] : 0;
    __syncthreads();
    for (int o = 1; o < 512; o <<= 1) {
        int u = (t >= o) ? s[t - o] : 0;
        __syncthreads();
        s[t] += u;
        __syncthreads();
    }
    if (i < n) tmp[i] = s[t];
    if (t == 511) bsum[blockIdx.x] = s[511];
}

__global__ __launch_bounds__(512) void k_scanB(int* __restrict__ bsum, int nb) {
    __shared__ int s[512];
    int t = threadIdx.x;
    s[t] = (t < nb) ? bsum[t] : 0;
    __syncthreads();
    for (int o = 1; o < 512; o <<= 1) {
        int u = (t >= o) ? s[t - o] : 0;
        __syncthreads();
        s[t] += u;
        __syncthreads();
    }
    if (t < nb) bsum[t] = s[t];
}

// rowptr + dinv fused
__global__ void k_scanC(const int* __restrict__ tmp, const int* __restrict__ bsum,
                        const int* __restrict__ cnt, int* __restrict__ rowptr,
                        float* __restrict__ dinv, int n) {
    int i = blockIdx.x * blockDim.x + threadIdx.x;
    if (i < n) {
        int b = i >> 9;
        int off = (b > 0) ? bsum[b - 1] : 0;
        rowptr[i + 1] = tmp[i] + off;
        if (i == 0) rowptr[0] = 0;
        dinv[i] = rsqrtf((float)(cnt[i] + 1));
    }
}

// fill packed (col, norm) pairs
__global__ void k_fill(const int* __restrict__ src, const int* __restrict__ dst,
                       const int* __restrict__ rowptr, int* __restrict__ cursor,
                       const float* __restrict__ dinv, int2* __restrict__ epk, int E) {
    int e = blockIdx.x * blockDim.x + threadIdx.x;
    if (e < E) {
        int s0 = src[e], d0 = dst[e];
        int p = atomicAdd(&cursor[d0], 1);
        int idx = rowptr[d0] + p;
        epk[idx] = make_int2(s0, __float_as_int(dinv[s0] * dinv[d0]));
    }
}

// ---------------- GEMM with fused BN-apply staging ----------------
// BNIN==0: stage Ain raw.
// BNIN==1: stage h = relu(bn(Ain)) (+res); write h IN PLACE into Aio (same buffer as Ain).
// ACT==0: C[n x 128] = staged @ W.   ACT==1: apre[r] = tanh(staged@W + b1) @ w2 + b2, track max.
#define FMA_ROW(i, a)                       \
    acc[i][0] = fmaf(a, w0.x, acc[i][0]);   \
    acc[i][1] = fmaf(a, w0.y, acc[i][1]);   \
    acc[i][2] = fmaf(a, w0.z, acc[i][2]);   \
    acc[i][3] = fmaf(a, w0.w, acc[i][3]);   \
    acc[i][4] = fmaf(a, w1.x, acc[i][4]);   \
    acc[i][5] = fmaf(a, w1.y, acc[i][5]);   \
    acc[i][6] = fmaf(a, w1.z, acc[i][6]);   \
    acc[i][7] = fmaf(a, w1.w, acc[i][7]);

template <int BNIN, int ACT>
__global__ __launch_bounds__(256, 3) void k_gemm(const float* __restrict__ Ain, float* __restrict__ Aio,
                                                 const float* __restrict__ res,
                                                 const float* __restrict__ csum, const float* __restrict__ csq,
                                                 const float* __restrict__ bng, const float* __restrict__ bnb,
                                                 const float* __restrict__ W, const float* __restrict__ bias,
                                                 float* __restrict__ C, const float* __restrict__ w2,
                                                 const float* __restrict__ b2, unsigned* __restrict__ gmax,
                                                 int n) {
    // hl padded to 132: A-column reads hl[ty+16i][k] spread banks ((132*16)%32 != 0).
    __shared__ float hl[64][132];   // 33.8 KB
    __shared__ float Ws[32][128];   // 16.4 KB  -> 50.2 KB total, 3 blocks/CU
    int tb = blockIdx.x * 64;
    int t = threadIdx.x;
    int rows = n - tb; if (rows > 64) rows = 64;
    int c4 = (t & 31) << 2;   // column group, constant across staging iters (256 % 32 == 0)

    float A0c = 0.f, A1c = 0.f, A2c = 0.f, A3c = 0.f;
    float B0c = 0.f, B1c = 0.f, B2c = 0.f, B3c = 0.f;
    if (BNIN) {
        float4 cs = *(const float4*)&csum[c4];
        float4 cq = *(const float4*)&csq[c4];
        float4 gg = *(const float4*)&bng[c4];
        float4 bb = *(const float4*)&bnb[c4];
        float inv_n = 1.0f / (float)n;
        float m0 = cs.x * inv_n, m1 = cs.y * inv_n, m2 = cs.z * inv_n, m3 = cs.w * inv_n;
        A0c = rsqrtf(cq.x * inv_n - m0 * m0 + EPS) * gg.x;
        A1c = rsqrtf(cq.y * inv_n - m1 * m1 + EPS) * gg.y;
        A2c = rsqrtf(cq.z * inv_n - m2 * m2 + EPS) * gg.z;
        A3c = rsqrtf(cq.w * inv_n - m3 * m3 + EPS) * gg.w;
        B0c = bb.x - m0 * A0c; B1c = bb.y - m1 * A1c; B2c = bb.z - m2 * A2c; B3c = bb.w - m3 * A3c;
    }
    for (int idx = t; idx < 64 * 32; idx += 256) {
        int r = idx >> 5;
        if (r < rows) {
            size_t go = (size_t)(tb + r) * HH + c4;
            float4 v = *(const float4*)&Ain[go];
            if (BNIN) {
                v.x = fmaxf(fmaf(v.x, A0c, B0c), 0.f);
                v.y = fmaxf(fmaf(v.y, A1c, B1c), 0.f);
                v.z = fmaxf(fmaf(v.z, A2c, B2c), 0.f);
                v.w = fmaxf(fmaf(v.w, A3c, B3c), 0.f);
                if (res) {
                    float4 rv = *(const float4*)&res[go];
                    v.x += rv.x; v.y += rv.y; v.z += rv.z; v.w += rv.w;
                }
                *(float4*)&Aio[go] = v;     // in-place h write (each elem touched once)
            }
            *(float4*)&hl[r][c4] = v;
        }
    }
    int tx = t & 15;       // owns cols 8*tx..8*tx+7
    int ty = t >> 4;       // owns rows ty + 16*i
    int tx8 = tx << 3;
    float acc[4][8] = {};
    for (int kc = 0; kc < 4; ++kc) {
        __syncthreads();   // hl ready (kc=0) / prev chunk compute done
        for (int idx = t; idx < 32 * 32; idx += 256) {
            int r = idx >> 5, cc4 = (idx & 31) << 2;
            *(float4*)&Ws[r][cc4] = *(const float4*)&W[(size_t)(kc * 32 + r) * HH + cc4];
        }
        __syncthreads();
        int kb = kc * 32;
        for (int k = 0; k < 32; ++k) {
            float4 w0 = *(const float4*)&Ws[k][tx8];
            float4 w1 = *(const float4*)&Ws[k][tx8 + 4];
            float a0 = hl[ty][kb + k];
            float a1 = hl[ty + 16][kb + k];
            float a2 = hl[ty + 32][kb + k];
            float a3 = hl[ty + 48][kb + k];
            FMA_ROW(0, a0)
            FMA_ROW(1, a1)
            FMA_ROW(2, a2)
            FMA_ROW(3, a3)
        }
    }
    if (ACT == 0) {
#pragma unroll
        for (int i = 0; i < 4; ++i) {
            int r = tb + ty + 16 * i;
            if (r < n) {
                float4 o0 = {acc[i][0], acc[i][1], acc[i][2], acc[i][3]};
                float4 o1 = {acc[i][4], acc[i][5], acc[i][6], acc[i][7]};
                *(float4*)&C[(size_t)r * HH + tx8] = o0;
                *(float4*)&C[(size_t)r * HH + tx8 + 4] = o1;
            }
        }
    } else {
        // fused attention GEMV: apre[r] = sum_c tanh(acc+b1[c]) * w2[c] + b2; track global max
        float b1v[8], w2v[8];
#pragma unroll
        for (int j = 0; j < 8; ++j) { b1v[j] = bias[tx8 + j]; w2v[j] = w2[tx8 + j]; }
        float b2s = b2[0];
        float lmax = -3.4e38f;
#pragma unroll
        for (int i = 0; i < 4; ++i) {
            float s = 0.f;
#pragma unroll
            for (int j = 0; j < 8; ++j)
                s = fmaf(tanhf(acc[i][j] + b1v[j]), w2v[j], s);
            s += __shfl_xor(s, 1);
            s += __shfl_xor(s, 2);
            s += __shfl_xor(s, 4);
            s += __shfl_xor(s, 8);
            int r = tb + ty + 16 * i;
            float val = s + b2s;
            if (r < n) {
                lmax = fmaxf(lmax, val);
                if (tx == 0) C[r] = val;
            }
        }
        lmax = fmaxf(lmax, __shfl_xor(lmax, 16));
        lmax = fmaxf(lmax, __shfl_xor(lmax, 32));
        __shared__ float wm[4];
        if ((t & 63) == 0) wm[t >> 6] = lmax;
        __syncthreads();
        if (t == 0) {
            float m = fmaxf(fmaxf(wm[0], wm[1]), fmaxf(wm[2], wm[3]));
            atomicMax(gmax, femax_enc(m));
        }
    }
}

// ---------------- Aggregation ----------------
#define AGG_FMA(vv, ww)                                           \
    acc.x = fmaf(vv.x, ww, acc.x); acc.y = fmaf(vv.y, ww, acc.y); \
    acc.z = fmaf(vv.z, ww, acc.z); acc.w = fmaf(vv.w, ww, acc.w);

__global__ __launch_bounds__(256) void k_agg(const float* __restrict__ z, const int* __restrict__ rowptr,
                                             const int2* __restrict__ epk, const float* __restrict__ dinv,
                                             const float* __restrict__ bias, float* __restrict__ agg, int n) {
    int wid = (int)((blockIdx.x * (size_t)blockDim.x + threadIdx.x) >> 6);
    if (wid >= n) return;
    int lane = threadIdx.x & 63;
    int half = lane >> 5;
    int c0 = (lane & 31) << 2;
    int beg = rowptr[wid], end = rowptr[wid + 1];
    float4 acc = {0.f, 0.f, 0.f, 0.f};
    if (half == 0) {
        float di = dinv[wid];
        float ws = di * di;
        float4 zs = *(const float4*)&z[(size_t)wid * HH + c0];
        acc.x = zs.x * ws; acc.y = zs.y * ws; acc.z = zs.z * ws; acc.w = zs.w * ws;
    }
    for (int e = beg + half; e < end; e += 16) {
        int2 p[8];
        float w[8];
#pragma unroll
        for (int j = 0; j < 8; ++j) {
            int idx = e + 2 * j;
            bool valid = idx < end;
            p[j] = epk[valid ? idx : beg];
            w[j] = valid ? __int_as_float(p[j].y) : 0.f;
        }
        float4 v[8];
#pragma unroll
        for (int j = 0; j < 8; ++j)
            v[j] = *(const float4*)&z[(size_t)p[j].x * HH + c0];
#pragma unroll
        for (int j = 0; j < 8; ++j) { AGG_FMA(v[j], w[j]) }
    }
    acc.x += __shfl_xor(acc.x, 32);
    acc.y += __shfl_xor(acc.y, 32);
    acc.z += __shfl_xor(acc.z, 32);
    acc.w += __shfl_xor(acc.w, 32);
    if (half == 0) {
        float4 b4 = *(const float4*)&bias[c0];
        acc.x += b4.x; acc.y += b4.y; acc.z += b4.z; acc.w += b4.w;
        *(float4*)&agg[(size_t)wid * HH + c0] = acc;
    }
}

// ---------------- BatchNorm stats ----------------
__global__ __launch_bounds__(256) void k_bnstats(const float* __restrict__ agg, float* __restrict__ colsum,
                                                 float* __restrict__ colsq, int n) {
    int t = threadIdx.x;
    int col = t & 127, sub = t >> 7;
    int rpb = (n + gridDim.x - 1) / gridDim.x;
    int r0 = blockIdx.x * rpb;
    int r1 = r0 + rpb; if (r1 > n) r1 = n;
    float s = 0.f, q = 0.f;
    for (int r = r0 + sub; r < r1; r += 2) {
        float v = agg[(size_t)r * HH + col];
        s += v;
        q = fmaf(v, v, q);
    }
    __shared__ float ls[256], lq[256];
    ls[t] = s; lq[t] = q;
    __syncthreads();
    if (t < 128) {
        atomicAdd(&colsum[col], ls[t] + ls[t + 128]);
        atomicAdd(&colsq[col], lq[t] + lq[t + 128]);
    }
}

// ---------------- Pooling (batch sorted) + global exp-sum ----------------
__global__ __launch_bounds__(256) void k_pool(const float* __restrict__ h, const float* __restrict__ apre,
                                              const int* __restrict__ batch, const unsigned* __restrict__ gmax,
                                              float* __restrict__ pooled, float* __restrict__ counts,
                                              float* __restrict__ Sglob, int n) {
    float M = femax_dec(*gmax);
    int t = threadIdx.x;
    int col = t & 127, sub = t >> 7;
    int rpb = (n + gridDim.x - 1) / gridDim.x;
    int r0 = blockIdx.x * rpb;
    int r1 = r0 + rpb; if (r1 > n) r1 = n;
    float acc = 0.f, cntf = 0.f, es = 0.f;
    int cur = -1;
    for (int r = r0 + sub; r < r1; r += 2) {
        int g = batch[r];
        if (g != cur) {
            if (cur >= 0) {
                atomicAdd(&pooled[cur * HH + col], acc);
                if (col == 0) atomicAdd(&counts[cur], cntf);
            }
            cur = g; acc = 0.f; cntf = 0.f;
        }
        float s = expf(apre[r] - M);
        acc = fmaf(h[(size_t)r * HH + col], s, acc);
        cntf += 1.0f;
        if (col == 0) es += s;
    }
    if (cur >= 0) {
        atomicAdd(&pooled[cur * HH + col], acc);
        if (col == 0) atomicAdd(&counts[cur], cntf);
    }
    if (col == 0 && es != 0.f) atomicAdd(Sglob, es);
}

// ---------------- Final MLP ----------------
__global__ __launch_bounds__(128) void k_mlp(const float* __restrict__ pooled, const float* __restrict__ counts,
                                             const float* __restrict__ Sglob, const float* __restrict__ W1,
                                             const float* __restrict__ b1, const float* __restrict__ W2,
                                             const float* __restrict__ b2, float* __restrict__ out) {
    int g = blockIdx.x;
    int t = threadIdx.x;
    __shared__ float p[128], t1[128];
    float S = Sglob[0];
    float c = fmaxf(counts[g], 1.0f);
    p[t] = pooled[g * HH + t] / (S * c);
    __syncthreads();
    float acc = b1[t];
    for (int k = 0; k < 128; ++k) acc = fmaf(p[k], W1[k * HH + t], acc);
    t1[t] = fmaxf(acc, 0.f);
    __syncthreads();
    float acc2 = b2[t];
    for (int j = 0; j < 128; ++j) acc2 = fmaf(t1[j], W2[j * HH + t], acc2);
    out[g * HH + t] = acc2;
}

extern "C" void kernel_launch(void* const* d_in, const int* in_sizes, int n_in,
                              void* d_out, int out_size, void* d_ws, size_t ws_size,
                              hipStream_t stream) {
    const float* x       = (const float*)d_in[0];
    const int*   ei      = (const int*)d_in[1];
    const int*   batch   = (const int*)d_in[2];
    const float* conv_w  = (const float*)d_in[3];
    const float* conv_b  = (const float*)d_in[4];
    const float* bn_g    = (const float*)d_in[5];
    const float* bn_b    = (const float*)d_in[6];
    const float* attn_w1 = (const float*)d_in[7];
    const float* attn_b1 = (const float*)d_in[8];
    const float* attn_w2 = (const float*)d_in[9];
    const float* attn_b2 = (const float*)d_in[10];
    const float* proj_w1 = (const float*)d_in[11];
    const float* proj_b1 = (const float*)d_in[12];
    const float* proj_w2 = (const float*)d_in[13];
    const float* proj_b2 = (const float*)d_in[14];

    const int E = in_sizes[1] / 2;
    const int n = in_sizes[2];
    const int* srcp = ei;
    const int* dstp = ei + E;

    // ---- workspace layout ----
    char* base = (char*)d_ws;
    size_t off = 0;
    auto alloc = [&](size_t bytes) -> char* {
        char* p = base + off;
        off = (off + bytes + 511) & ~(size_t)511;
        return p;
    };
    int*   cntcur  = (int*)alloc((size_t)2 * n * 4);     // cnt | cursor (one memset)
    int*   cnt     = cntcur;
    int*   cursor  = cntcur + n;
    int*   rowptr  = (int*)alloc((size_t)(n + 1) * 4);
    int*   tmp     = (int*)alloc((size_t)n * 4);
    int*   bsum    = (int*)alloc(512 * 4);
    float* dinv    = (float*)alloc((size_t)n * 4);
    int2*  epk     = (int2*)alloc((size_t)E * 8);
    float* z       = (float*)alloc((size_t)n * HH * 4);
    float* aggA    = (float*)alloc((size_t)n * HH * 4);
    float* aggB    = (float*)alloc((size_t)n * HH * 4);
    float* apre    = (float*)alloc((size_t)n * 4);
    // zero arena: colstats(3*256 floats) | gmax(1) | S(1) | pad->1024 | pooled(8192) | counts(64)
    float* zarena  = (float*)alloc((size_t)(1024 + GG * HH + GG) * 4);
    float* cs0 = zarena;            float* cq0 = zarena + 128;
    float* cs1 = zarena + 256;      float* cq1 = zarena + 384;
    float* cs2 = zarena + 512;      float* cq2 = zarena + 640;
    unsigned* gmaxu = (unsigned*)(zarena + 768);
    float* Sglob  = zarena + 769;
    float* pooled = zarena + 1024;
    float* counts = zarena + 1024 + GG * HH;
    const size_t zbytes = (size_t)(1024 + GG * HH + GG) * 4;

    const int eGrid    = (E + 255) / 256;
    const int nGrid    = (n + 255) / 256;
    const int nbScan   = (n + 511) / 512;
    const int gemmGrid = (n + 63) / 64;
    const int waveGrid = (n + 3) / 4;

    // ---- zero accumulators + CSR build ----
    hipMemsetAsync(zarena, 0, zbytes, stream);
    hipMemsetAsync(cntcur, 0, (size_t)2 * n * 4, stream);
    k_count<<<eGrid, 256, 0, stream>>>(dstp, cnt, E);
    k_scanA<<<nbScan, 512, 0, stream>>>(cnt, tmp, bsum, n);
    k_scanB<<<1, 512, 0, stream>>>(bsum, nbScan);
    k_scanC<<<nGrid, 256, 0, stream>>>(tmp, bsum, cnt, rowptr, dinv, n);
    k_fill<<<eGrid, 256, 0, stream>>>(srcp, dstp, rowptr, cursor, dinv, epk, E);

    // ---- layer 0 ----
    k_gemm<0, 0><<<gemmGrid, 256, 0, stream>>>(x, nullptr, nullptr, nullptr, nullptr, nullptr, nullptr,
                                               conv_w, nullptr, z, nullptr, nullptr, nullptr, n);
    k_agg<<<waveGrid, 256, 0, stream>>>(z, rowptr, epk, dinv, conv_b, aggA, n);
    k_bnstats<<<1024, 256, 0, stream>>>(aggA, cs0, cq0, n);

    // ---- layer 1 (BN0 fused into staging; h1 -> aggA in place) ----
    k_gemm<1, 0><<<gemmGrid, 256, 0, stream>>>(aggA, aggA, nullptr, cs0, cq0, bn_g, bn_b,
                                               conv_w + (size_t)HH * HH, nullptr, z, nullptr, nullptr,
                                               nullptr, n);
    k_agg<<<waveGrid, 256, 0, stream>>>(z, rowptr, epk, dinv, conv_b + HH, aggB, n);
    k_bnstats<<<1024, 256, 0, stream>>>(aggB, cs1, cq1, n);

    // ---- layer 2 (BN1 fused; res=h1(aggA); h2 -> aggB in place) ----
    k_gemm<1, 0><<<gemmGrid, 256, 0, stream>>>(aggB, aggB, aggA, cs1, cq1, bn_g + HH, bn_b + HH,
                                               conv_w + (size_t)2 * HH * HH, nullptr, z, nullptr, nullptr,
                                               nullptr, n);
    k_agg<<<waveGrid, 256, 0, stream>>>(z, rowptr, epk, dinv, conv_b + 2 * HH, aggA, n);
    k_bnstats<<<1024, 256, 0, stream>>>(aggA, cs2, cq2, n);

    // ---- attention gemm (BN2 fused; res=h2(aggB); h3 -> aggA in place; GEMV+max epilogue) ----
    k_gemm<1, 1><<<gemmGrid, 256, 0, stream>>>(aggA, aggA, aggB, cs2, cq2, bn_g + 2 * HH, bn_b + 2 * HH,
                                               attn_w1, attn_b1, apre, attn_w2, attn_b2, gmaxu, n);

    // ---- pooling (+ global exp-sum) + MLP ----
    k_pool<<<1024, 256, 0, stream>>>(aggA, apre, batch, gmaxu, pooled, counts, Sglob, n);
    k_mlp<<<GG, 128, 0, stream>>>(pooled, counts, Sglob, proj_w1, proj_b1, proj_w2, proj_b2,
                                  (float*)d_out);
}